// Round 2
// baseline (2402.270 us; speedup 1.0000x reference)
//
#include <hip/hip_runtime.h>
#include <hip/hip_bf16.h>

// ---------------------------------------------------------------------------
// MultiFieldAxialAttention on MI355X (gfx950)
// B=32, T=12, LA=12, LO=12, D0=1024, D1=512, H=8+8, E=64
// Buffer plan (ws ~178 MB):
//   d_out  <- qkv scratch [N0,2048] bf16 for all layers (exact size match),
//             final layer overwrites with fp32 result
//   layers 0,1: attn writes o_self->qkv[:,0:512], o_cross->qkv[:,1536:2048];
//               out-proj reads split-A (k<512 -> k, k>=512 -> k+1024)
//   layer 2:    attn writes into f0 (dead), out-proj reads f0 + x0 -> d_out
// ---------------------------------------------------------------------------

typedef __bf16 bf16x8 __attribute__((ext_vector_type(8)));
typedef float floatx4 __attribute__((ext_vector_type(4)));

#define N0 55296   // 32*12*12*12 tokens of field0
#define N1 13824   // 32*12*6*6 tokens of field1

__device__ __forceinline__ void gload16(const void* g, void* l) {
    __builtin_amdgcn_global_load_lds(
        (const __attribute__((address_space(1))) unsigned int*)g,
        (__attribute__((address_space(3))) unsigned int*)l, 16, 0, 0);
}

// ---------------------------------------------------------------------------
// LayerNorm (elementwise_affine=False): fp32 in -> bf16 out, 1 block per row
// ---------------------------------------------------------------------------
template <int D>
__global__ __launch_bounds__(256)
void ln_kernel(const float* __restrict__ x, __hip_bfloat16* __restrict__ y)
{
    const int row = blockIdx.x;
    const int tid = threadIdx.x;
    const float* xr = x + (size_t)row * D;
    float vals[D / 256];
    float s = 0.f, q = 0.f;
#pragma unroll
    for (int k = 0; k < D / 256; ++k) {
        float v = xr[tid + k * 256];
        vals[k] = v; s += v; q += v * v;
    }
#pragma unroll
    for (int off = 32; off > 0; off >>= 1) {
        s += __shfl_xor(s, off);
        q += __shfl_xor(q, off);
    }
    __shared__ float rs[4], rq[4];
    const int w = tid >> 6;
    if ((tid & 63) == 0) { rs[w] = s; rq[w] = q; }
    __syncthreads();
    s = rs[0] + rs[1] + rs[2] + rs[3];
    q = rq[0] + rq[1] + rq[2] + rq[3];
    const float mean = s * (1.f / D);
    const float var  = q * (1.f / D) - mean * mean;
    const float rstd = rsqrtf(var + 1e-5f);
    __hip_bfloat16* yr = y + (size_t)row * D;
#pragma unroll
    for (int k = 0; k < D / 256; ++k)
        yr[tid + k * 256] = __float2bfloat16((vals[k] - mean) * rstd);
}

// ---------------------------------------------------------------------------
// Weight transpose: in [K][N] fp32 -> out [N][K] bf16
// ---------------------------------------------------------------------------
__global__ __launch_bounds__(256)
void transpose_kernel(const float* __restrict__ in, __hip_bfloat16* __restrict__ out,
                      int K, int N)
{
    __shared__ float tile[32][33];
    const int n0 = blockIdx.x * 32, k0 = blockIdx.y * 32;
    const int tx = threadIdx.x & 31, ty = threadIdx.x >> 5; // 32 x 8
#pragma unroll
    for (int d = 0; d < 4; ++d)
        tile[ty + d * 8][tx] = in[(size_t)(k0 + ty + d * 8) * N + n0 + tx];
    __syncthreads();
#pragma unroll
    for (int d = 0; d < 4; ++d)
        out[(size_t)(n0 + ty + d * 8) * K + k0 + tx] = __float2bfloat16(tile[tx][ty + d * 8]);
}

// ---------------------------------------------------------------------------
// bf16 MFMA GEMM: C[M,N] = A[M,K] @ Bt[N,K]^T
// 128x128 tile, BK=64, 4 waves, 16x16x32 MFMA, global_load_lds 16B staging,
// XOR-swizzled LDS (pre-swizzled global source + swizzled ds_read, rule 21).
// ASPLIT: logical k<512 -> phys col k ; k>=512 -> phys col k+1024 (lda=2048)
// EPI: 0 = bf16 ; 1 = bf16 + bias ; 2 = fp32 + bias + resid
// ---------------------------------------------------------------------------
template <int EPI, bool ASPLIT>
__global__ __launch_bounds__(256)
void gemm_bt(const __hip_bfloat16* __restrict__ A,
             const __hip_bfloat16* __restrict__ Bt,
             void* __restrict__ Cv,
             const float* __restrict__ bias,
             const float* __restrict__ resid,
             int M, int N, int K, int lda)
{
    __shared__ __align__(16) char lds[32768];
    char* ldsA = lds;
    char* ldsB = lds + 16384;

    const int t    = threadIdx.x;
    const int m0   = blockIdx.y * 128;
    const int n0   = blockIdx.x * 128;
    const int w    = t >> 6;
    const int lane = t & 63;
    const int wr   = w >> 1;
    const int wc   = w & 1;
    const int fr   = lane & 15;
    const int ksl  = lane >> 4;

    floatx4 acc[4][4] = {};

    const int srow = t >> 3;
    const int scg  = t & 7;
    const __hip_bfloat16* aptr[4];
    const __hip_bfloat16* bptr[4];
    int ldsoff[4];
#pragma unroll
    for (int c = 0; c < 4; ++c) {
        const int row = c * 32 + srow;
        const int col = (scg ^ (row & 7)) << 3;   // pre-swizzled source column
        aptr[c] = A  + (size_t)(m0 + row) * lda + col;
        bptr[c] = Bt + (size_t)(n0 + row) * K + col;
        ldsoff[c] = c * 4096 + (w << 10);          // wave-uniform base
    }

    int aoff[2][4], boff[2][4];
#pragma unroll
    for (int kk = 0; kk < 2; ++kk) {
#pragma unroll
        for (int m = 0; m < 4; ++m) {
            const int cg   = kk * 4 + ksl;
            const int rowA = wr * 64 + m * 16 + fr;
            aoff[kk][m] = rowA * 128 + ((cg ^ (rowA & 7)) << 4);
            const int rowB = wc * 64 + m * 16 + fr;
            boff[kk][m] = rowB * 128 + ((cg ^ (rowB & 7)) << 4);
        }
    }

    for (int k0 = 0; k0 < K; k0 += 64) {
        const int ka = ASPLIT ? (k0 >= 512 ? k0 + 1024 : k0) : k0;
#pragma unroll
        for (int c = 0; c < 4; ++c)
            gload16(aptr[c] + ka, ldsA + ldsoff[c]);
#pragma unroll
        for (int c = 0; c < 4; ++c)
            gload16(bptr[c] + k0, ldsB + ldsoff[c]);
        __syncthreads();
#pragma unroll
        for (int kk = 0; kk < 2; ++kk) {
            bf16x8 af[4], bfv[4];
#pragma unroll
            for (int m = 0; m < 4; ++m) af[m]  = *(const bf16x8*)(ldsA + aoff[kk][m]);
#pragma unroll
            for (int n = 0; n < 4; ++n) bfv[n] = *(const bf16x8*)(ldsB + boff[kk][n]);
#pragma unroll
            for (int m = 0; m < 4; ++m)
#pragma unroll
                for (int n = 0; n < 4; ++n)
                    acc[m][n] = __builtin_amdgcn_mfma_f32_16x16x32_bf16(af[m], bfv[n], acc[m][n], 0, 0, 0);
        }
        __syncthreads();
    }

#pragma unroll
    for (int m = 0; m < 4; ++m) {
#pragma unroll
        for (int n = 0; n < 4; ++n) {
            const int col = n0 + wc * 64 + n * 16 + fr;
#pragma unroll
            for (int r = 0; r < 4; ++r) {
                const int row = m0 + wr * 64 + m * 16 + ksl * 4 + r;
                const size_t idx = (size_t)row * N + col;
                const float v = acc[m][n][r];
                if (EPI == 0) {
                    ((__hip_bfloat16*)Cv)[idx] = __float2bfloat16(v);
                } else if (EPI == 1) {
                    ((__hip_bfloat16*)Cv)[idx] = __float2bfloat16(v + bias[col]);
                } else {
                    ((float*)Cv)[idx] = resid[idx] + v + bias[col];
                }
            }
        }
    }
}

// ---------------------------------------------------------------------------
// Axial attention. One block (256 thr) per (group, self/cross).
// qkv: [N0,2048] = [q_self | k_self | v_self | q_cross]
// kvc: [N1,1024] = [k_cross | v_cross]
// Output: oc[token*ldo + (cross?cross_off:0) + c], c in [0,512)
// ---------------------------------------------------------------------------
__global__ __launch_bounds__(256)
void attn_kernel(const __hip_bfloat16* __restrict__ qkv,
                 const __hip_bfloat16* __restrict__ kvc,
                 __hip_bfloat16* __restrict__ oc, int ldo, int cross_off,
                 int ip)
{
    __shared__ __align__(16) __hip_bfloat16 Qs[12][520];
    __shared__ __align__(16) __hip_bfloat16 Ks[12][520];
    __shared__ __align__(16) __hip_bfloat16 Vs[12][520];
    __shared__ float P[8][12][12];

    const int g = blockIdx.x;
    const bool cross = blockIdx.y != 0;
    const int tid = threadIdx.x;

    const int b  = g / 144;
    const int r1 = (g % 144) / 12;
    const int r2 = g % 12;
    int n_base, qstride, kvb, kvstride, tk;
    if (ip == 0) {          // attend over T
        n_base = b * 1728 + r1 * 12 + r2; qstride = 144;
        kvb = b * 432 + (r1 >> 1) * 6 + (r2 >> 1); kvstride = 36; tk = 12;
    } else if (ip == 1) {   // attend over LA
        n_base = b * 1728 + r1 * 144 + r2; qstride = 12;
        kvb = b * 432 + r1 * 36 + (r2 >> 1); kvstride = 6; tk = 6;
    } else {                // attend over LO
        n_base = b * 1728 + r1 * 144 + r2 * 12; qstride = 1;
        kvb = b * 432 + r1 * 36 + (r2 >> 1) * 6; kvstride = 1; tk = 6;
    }
    if (!cross) tk = 12;

    // ---- stage Q (12 rows x 512 bf16 = 64 uint4 per row)
    const int qoff = cross ? 1536 : 0;
    for (int idx = tid; idx < 12 * 64; idx += 256) {
        const int i = idx >> 6, c = idx & 63;
        const uint4* src = (const uint4*)(qkv + (size_t)(n_base + i * qstride) * 2048 + qoff);
        *(uint4*)(&Qs[i][c * 8]) = src[c];
    }
    // ---- stage K/V
    if (!cross) {
        for (int idx = tid; idx < 12 * 64; idx += 256) {
            const int j = idx >> 6, c = idx & 63;
            const __hip_bfloat16* row = qkv + (size_t)(n_base + j * qstride) * 2048;
            *(uint4*)(&Ks[j][c * 8]) = ((const uint4*)(row + 512))[c];
            *(uint4*)(&Vs[j][c * 8]) = ((const uint4*)(row + 1024))[c];
        }
    } else {
        for (int idx = tid; idx < tk * 64; idx += 256) {
            const int j = idx >> 6, c = idx & 63;
            const __hip_bfloat16* row = kvc + (size_t)(kvb + j * kvstride) * 1024;
            *(uint4*)(&Ks[j][c * 8]) = ((const uint4*)(row))[c];
            *(uint4*)(&Vs[j][c * 8]) = ((const uint4*)(row + 512))[c];
        }
    }
    __syncthreads();

    // ---- dots: P[h][i][j] = (q_i . k_j) * E^-0.5
    const int ndots = 8 * 12 * tk;
    for (int idx = tid; idx < ndots; idx += 256) {
        const int h = idx / (12 * tk);
        const int rem = idx % (12 * tk);
        const int i = rem / tk, j = rem % tk;
        const __hip_bfloat162* q2 = (const __hip_bfloat162*)(&Qs[i][h * 64]);
        const __hip_bfloat162* k2 = (const __hip_bfloat162*)(&Ks[j][h * 64]);
        float s = 0.f;
#pragma unroll
        for (int e = 0; e < 32; ++e) {
            const float2 qf = __bfloat1622float2(q2[e]);
            const float2 kf = __bfloat1622float2(k2[e]);
            s += qf.x * kf.x + qf.y * kf.y;
        }
        P[h][i][j] = s * 0.125f;
    }
    __syncthreads();

    // ---- softmax over j
    if (tid < 96) {
        const int h = tid / 12, i = tid % 12;
        float mx = -1e30f;
        for (int j = 0; j < tk; ++j) mx = fmaxf(mx, P[h][i][j]);
        float sum = 0.f;
        for (int j = 0; j < tk; ++j) { const float e = __expf(P[h][i][j] - mx); P[h][i][j] = e; sum += e; }
        const float inv = 1.f / sum;
        for (int j = 0; j < tk; ++j) P[h][i][j] *= inv;
    }
    __syncthreads();

    // ---- out: o[i][c] = sum_j P[h][i][j] * V[j][c]
    for (int idx = tid; idx < 12 * 512; idx += 256) {
        const int i = idx >> 9, c = idx & 511;
        const int h = c >> 6;
        float a = 0.f;
        for (int j = 0; j < tk; ++j)
            a += P[h][i][j] * __bfloat162float(Vs[j][c]);
        oc[(size_t)(n_base + i * qstride) * ldo + (cross ? cross_off : 0) + c] = __float2bfloat16(a);
    }
}

// ---------------------------------------------------------------------------
extern "C" void kernel_launch(void* const* d_in, const int* in_sizes, int n_in,
                              void* d_out, int out_size, void* d_ws, size_t ws_size,
                              hipStream_t stream)
{
    (void)in_sizes; (void)n_in; (void)out_size; (void)ws_size;
    const float* x0        = (const float*)d_in[0];
    const float* x1        = (const float*)d_in[1];
    const float* wq_self   = (const float*)d_in[2];
    const float* wkv_self  = (const float*)d_in[3];
    const float* wq_cross  = (const float*)d_in[4];
    const float* wkv_cross = (const float*)d_in[5];
    const float* w_out     = (const float*)d_in[6];
    const float* b_out     = (const float*)d_in[7];

    // d_out doubles as the qkv scratch: 55296*2048*2 B == out_size*4 B exactly
    __hip_bfloat16* qkv = (__hip_bfloat16*)d_out;

    char* ws = (char*)d_ws;
    size_t off = 0;
    auto alloc = [&](size_t bytes) {
        void* p = ws + off;
        off += (bytes + 255) & ~(size_t)255;
        return p;
    };
    __hip_bfloat16* f0  = (__hip_bfloat16*)alloc((size_t)N0 * 1024 * 2);
    __hip_bfloat16* f1  = (__hip_bfloat16*)alloc((size_t)N1 * 512 * 2);
    __hip_bfloat16* kvc = (__hip_bfloat16*)alloc((size_t)N1 * 1024 * 2);
    __hip_bfloat16* W1t = (__hip_bfloat16*)alloc((size_t)3 * 2048 * 1024 * 2);
    __hip_bfloat16* W2t = (__hip_bfloat16*)alloc((size_t)3 * 1024 * 512 * 2);
    __hip_bfloat16* W3t = (__hip_bfloat16*)alloc((size_t)3 * 1024 * 1024 * 2);

    // layernorms
    ln_kernel<1024><<<N0, 256, 0, stream>>>(x0, f0);
    ln_kernel<512><<<N1, 256, 0, stream>>>(x1, f1);

    // weight transposes into B^T (bf16)
    for (int ip = 0; ip < 3; ++ip) {
        transpose_kernel<<<dim3(16, 32), 256, 0, stream>>>(
            wq_self + (size_t)ip * 1024 * 512, W1t + (size_t)ip * 2048 * 1024, 1024, 512);
        transpose_kernel<<<dim3(32, 32), 256, 0, stream>>>(
            wkv_self + (size_t)ip * 1024 * 1024, W1t + (size_t)ip * 2048 * 1024 + (size_t)512 * 1024, 1024, 1024);
        transpose_kernel<<<dim3(16, 32), 256, 0, stream>>>(
            wq_cross + (size_t)ip * 1024 * 512, W1t + (size_t)ip * 2048 * 1024 + (size_t)1536 * 1024, 1024, 512);
        transpose_kernel<<<dim3(32, 16), 256, 0, stream>>>(
            wkv_cross + (size_t)ip * 512 * 1024, W2t + (size_t)ip * 1024 * 512, 512, 1024);
        transpose_kernel<<<dim3(32, 32), 256, 0, stream>>>(
            w_out + (size_t)ip * 1024 * 1024, W3t + (size_t)ip * 1024 * 1024, 1024, 1024);
    }

    // 3 axial layers
    for (int ip = 0; ip < 3; ++ip) {
        // fused qkv projection: [N0,1024] @ [1024,2048] -> d_out
        gemm_bt<0, false><<<dim3(16, N0 / 128), 256, 0, stream>>>(
            f0, W1t + (size_t)ip * 2048 * 1024, qkv, nullptr, nullptr, N0, 2048, 1024, 1024);
        // cross kv projection: [N1,512] @ [512,1024] -> kvc
        gemm_bt<0, false><<<dim3(8, N1 / 128), 256, 0, stream>>>(
            f1, W2t + (size_t)ip * 1024 * 512, kvc, nullptr, nullptr, N1, 1024, 512, 512);
        if (ip < 2) {
            // attention writes o_self -> qkv[:,0:512], o_cross -> qkv[:,1536:2048]
            attn_kernel<<<dim3(4608, 2), 256, 0, stream>>>(qkv, kvc, qkv, 2048, 1536, ip);
            // out-proj with split-A read, writes new f0 (bf16 + bias)
            gemm_bt<1, true><<<dim3(8, N0 / 128), 256, 0, stream>>>(
                qkv, W3t + (size_t)ip * 1024 * 1024, f0, b_out + ip * 1024, nullptr,
                N0, 1024, 1024, 2048);
        } else {
            // attention writes [o_self|o_cross] into f0 (dead here)
            attn_kernel<<<dim3(4608, 2), 256, 0, stream>>>(qkv, kvc, f0, 1024, 512, ip);
            // final out-proj: f0 @ W3t + bias + x0 -> d_out (fp32)
            gemm_bt<2, false><<<dim3(8, N0 / 128), 256, 0, stream>>>(
                f0, W3t + (size_t)ip * 1024 * 1024, d_out, b_out + ip * 1024, x0,
                N0, 1024, 1024, 1024);
        }
    }
}

// Round 3
// 1870.467 us; speedup vs baseline: 1.2843x; 1.2843x over previous
//
#include <hip/hip_runtime.h>
#include <hip/hip_bf16.h>

// ---------------------------------------------------------------------------
// MultiFieldAxialAttention on MI355X (gfx950)
// B=32, T=12, LA=12, LO=12, D0=1024, D1=512, H=8+8, E=64
// GEMMs: 256x256x64 8-phase counted-vmcnt template (T1+T2+T3+T4+T5)
// ---------------------------------------------------------------------------

typedef __bf16 bf16x8 __attribute__((ext_vector_type(8)));
typedef float floatx4 __attribute__((ext_vector_type(4)));

#define N0 55296   // 32*12*12*12 tokens of field0
#define N1 13824   // 32*12*6*6 tokens of field1

#define RAW_BARRIER() asm volatile("s_barrier" ::: "memory")
#define VMCNT(n) asm volatile("s_waitcnt vmcnt(" #n ")" ::: "memory")

__device__ __forceinline__ void gload16(const void* g, void* l) {
    __builtin_amdgcn_global_load_lds(
        (const __attribute__((address_space(1))) unsigned int*)g,
        (__attribute__((address_space(3))) unsigned int*)l, 16, 0, 0);
}

// ---------------------------------------------------------------------------
// LayerNorm (elementwise_affine=False): fp32 in -> bf16 out, 1 block per row
// ---------------------------------------------------------------------------
template <int D>
__global__ __launch_bounds__(256)
void ln_kernel(const float* __restrict__ x, __hip_bfloat16* __restrict__ y)
{
    const int row = blockIdx.x;
    const int tid = threadIdx.x;
    const float* xr = x + (size_t)row * D;
    float vals[D / 256];
    float s = 0.f, q = 0.f;
#pragma unroll
    for (int k = 0; k < D / 256; ++k) {
        float v = xr[tid + k * 256];
        vals[k] = v; s += v; q += v * v;
    }
#pragma unroll
    for (int off = 32; off > 0; off >>= 1) {
        s += __shfl_xor(s, off);
        q += __shfl_xor(q, off);
    }
    __shared__ float rs[4], rq[4];
    const int w = tid >> 6;
    if ((tid & 63) == 0) { rs[w] = s; rq[w] = q; }
    __syncthreads();
    s = rs[0] + rs[1] + rs[2] + rs[3];
    q = rq[0] + rq[1] + rq[2] + rq[3];
    const float mean = s * (1.f / D);
    const float var  = q * (1.f / D) - mean * mean;
    const float rstd = rsqrtf(var + 1e-5f);
    __hip_bfloat16* yr = y + (size_t)row * D;
#pragma unroll
    for (int k = 0; k < D / 256; ++k)
        yr[tid + k * 256] = __float2bfloat16((vals[k] - mean) * rstd);
}

// ---------------------------------------------------------------------------
// Weight transpose: in [K][N] fp32 -> out [N][K] bf16
// ---------------------------------------------------------------------------
__global__ __launch_bounds__(256)
void transpose_kernel(const float* __restrict__ in, __hip_bfloat16* __restrict__ out,
                      int K, int N)
{
    __shared__ float tile[32][33];
    const int n0 = blockIdx.x * 32, k0 = blockIdx.y * 32;
    const int tx = threadIdx.x & 31, ty = threadIdx.x >> 5; // 32 x 8
#pragma unroll
    for (int d = 0; d < 4; ++d)
        tile[ty + d * 8][tx] = in[(size_t)(k0 + ty + d * 8) * N + n0 + tx];
    __syncthreads();
#pragma unroll
    for (int d = 0; d < 4; ++d)
        out[(size_t)(n0 + ty + d * 8) * K + k0 + tx] = __float2bfloat16(tile[tx][ty + d * 8]);
}

// ---------------------------------------------------------------------------
// 256x256 8-phase bf16 MFMA GEMM: C[M,N] = A[M,K] @ Bt[N,K]^T
// 512 thr = 8 waves (2 Mx4 N), per-wave 128x64 out, BK=64, dbuf LDS 128 KiB.
// K-tile split into 4 half-tiles: A-h0 (m-frags 0-3), A-h1 (m 4-7),
// B-h0 (n 0-1), B-h1 (n 2-3); staged in scattered row order so each phase
// consumes exactly one half-tile. FIFO prefetch A0,B0,A1,B1 one tile ahead;
// uniform s_waitcnt vmcnt(4) at phase ends keeps 2 half-tiles in flight.
// XOR swizzle (row&7) on 16B col-groups: pre-swizzled global src + swizzled
// ds_read (rule 21); measured 0 bank conflicts with this scheme.
// ASPLIT: logical k<512 -> phys col k ; k>=512 -> col k+1024 (lda=2048)
// EPI: 0 = bf16 ; 1 = bf16 + bias ; 2 = fp32 + bias + resid
// ---------------------------------------------------------------------------
template <int EPI, bool ASPLIT>
__global__ __launch_bounds__(512)
void gemm8p(const __hip_bfloat16* __restrict__ A,
            const __hip_bfloat16* __restrict__ Bt,
            void* __restrict__ Cv,
            const float* __restrict__ bias,
            const float* __restrict__ resid,
            int M, int N, int K, int lda)
{
    __shared__ __align__(16) char lds[131072];

    // bijective XCD swizzle (all grids are multiples of 8 workgroups)
    const int gx  = gridDim.x;
    const int nwg = gx * gridDim.y;
    const int bid = blockIdx.y * gx + blockIdx.x;
    const int swz = (bid & 7) * (nwg >> 3) + (bid >> 3);
    const int m0 = (swz / gx) * 256;
    const int n0 = (swz % gx) * 256;

    const int t    = threadIdx.x;
    const int w    = t >> 6;
    const int lane = t & 63;
    const int wr   = w >> 2;     // 0..1  (M half)
    const int wc   = w & 3;      // 0..3  (N quarter)
    const int fr   = lane & 15;
    const int ksl  = lane >> 4;

    floatx4 acc[8][4] = {};

    // ---- staging source bases (pre-swizzled col: key = local row & 7)
    const int tr   = t >> 3;                      // 0..63
    const int scol = ((t & 7) ^ (tr & 7)) << 3;
    const __hip_bfloat16* aG = A  + (size_t)(m0 + tr) * lda + scol;
    const __hip_bfloat16* bG = Bt + (size_t)(n0 + ((tr >> 5) * 64) + (tr & 31)) * K + scol;
    const int ldst = t * 16;                      // linear LDS dest (wave-uniform + lane*16)

    // ---- ds_read per-thread base offsets (kk=1 via ^64)
    const int cg0 = ksl ^ (fr & 7);
    const int aO0 = (wr * 64 + fr) * 128 + cg0 * 16;
    const int bO0 = (wc * 32 + fr) * 128 + cg0 * 16;

    // LDS map per buffer (65536 B): A-h0 @0, A-h1 @16384, B-h0 @32768, B-h1 @49152
    auto stageA = [&](char* buf, int h, int ka) {
        gload16(aG + ka + (size_t)(h * 64)       * lda, buf + h * 16384 + ldst);
        gload16(aG + ka + (size_t)(h * 64 + 128) * lda, buf + h * 16384 + 8192 + ldst);
    };
    auto stageB = [&](char* buf, int h, int kb) {
        gload16(bG + kb + (size_t)(h * 32)       * K, buf + 32768 + h * 16384 + ldst);
        gload16(bG + kb + (size_t)(h * 32 + 128) * K, buf + 32768 + h * 16384 + 8192 + ldst);
    };

    const char* bufC = lds;
    auto ldA = [&](int h, bf16x8 (&a)[2][4]) {
#pragma unroll
        for (int mm = 0; mm < 4; ++mm) {
            a[0][mm] = *(const bf16x8*)(bufC + h * 16384 + mm * 2048 + aO0);
            a[1][mm] = *(const bf16x8*)(bufC + h * 16384 + mm * 2048 + (aO0 ^ 64));
        }
    };
    auto ldB = [&](int h, bf16x8 (&b)[2][2]) {
#pragma unroll
        for (int nn = 0; nn < 2; ++nn) {
            b[0][nn] = *(const bf16x8*)(bufC + 32768 + h * 16384 + nn * 2048 + bO0);
            b[1][nn] = *(const bf16x8*)(bufC + 32768 + h * 16384 + nn * 2048 + (bO0 ^ 64));
        }
    };
    auto quad = [&](bf16x8 (&a)[2][4], bf16x8 (&b)[2][2], int mlo, int nlo) {
        __builtin_amdgcn_s_setprio(1);
#pragma unroll
        for (int kk = 0; kk < 2; ++kk)
#pragma unroll
            for (int mm = 0; mm < 4; ++mm)
#pragma unroll
                for (int nn = 0; nn < 2; ++nn)
                    acc[mlo + mm][nlo + nn] = __builtin_amdgcn_mfma_f32_16x16x32_bf16(
                        a[kk][mm], b[kk][nn], acc[mlo + mm][nlo + nn], 0, 0, 0);
        __builtin_amdgcn_s_setprio(0);
    };

    const int NT = K >> 6;

    // prologue: tile 0 -> buf0, FIFO order A0,B0,A1,B1
    stageA(lds, 0, 0);
    stageB(lds, 0, 0);
    stageA(lds, 1, 0);
    stageB(lds, 1, 0);
    VMCNT(4);
    RAW_BARRIER();

    bf16x8 a0[2][4], a1[2][4], b0[2][2], b1[2][2];

    for (int tt = 0; tt < NT - 1; ++tt) {
        bufC = lds + ((tt & 1) << 16);
        char* bufN = lds + (((tt + 1) & 1) << 16);
        const int kc = (tt + 1) << 6;
        const int ka = ASPLIT ? (kc >= 512 ? kc + 1024 : kc) : kc;
        // P0: read A-h0,B-h0(tt); prefetch A-h0(tt+1); MFMA quad(m0-3, n0-1)
        ldA(0, a0); ldB(0, b0);
        stageA(bufN, 0, ka);
        RAW_BARRIER(); __builtin_amdgcn_sched_barrier(0);
        quad(a0, b0, 0, 0);
        VMCNT(4); RAW_BARRIER();
        // P1: read A-h1(tt); prefetch B-h0(tt+1); MFMA quad(m4-7, n0-1)
        ldA(1, a1);
        stageB(bufN, 0, kc);
        RAW_BARRIER(); __builtin_amdgcn_sched_barrier(0);
        quad(a1, b0, 4, 0);
        VMCNT(4); RAW_BARRIER();
        // P2: read B-h1(tt); prefetch A-h1(tt+1); MFMA quad(m0-3, n2-3)
        ldB(1, b1);
        stageA(bufN, 1, ka);
        RAW_BARRIER(); __builtin_amdgcn_sched_barrier(0);
        quad(a0, b1, 0, 2);
        RAW_BARRIER();
        // P3: prefetch B-h1(tt+1); MFMA quad(m4-7, n2-3)
        stageB(bufN, 1, kc);
        RAW_BARRIER(); __builtin_amdgcn_sched_barrier(0);
        quad(a1, b1, 4, 2);
        VMCNT(4); RAW_BARRIER();
    }

    // tail tile NT-1 (no prefetch): waits shrink 2 -> 0
    bufC = lds + (((NT - 1) & 1) << 16);
    ldA(0, a0); ldB(0, b0);
    RAW_BARRIER(); __builtin_amdgcn_sched_barrier(0);
    quad(a0, b0, 0, 0);
    VMCNT(2); RAW_BARRIER();
    ldA(1, a1);
    RAW_BARRIER(); __builtin_amdgcn_sched_barrier(0);
    quad(a1, b0, 4, 0);
    VMCNT(0); RAW_BARRIER();
    ldB(1, b1);
    RAW_BARRIER(); __builtin_amdgcn_sched_barrier(0);
    quad(a0, b1, 0, 2);
    quad(a1, b1, 4, 2);

    // ---- epilogue
#pragma unroll
    for (int m = 0; m < 8; ++m) {
#pragma unroll
        for (int n = 0; n < 4; ++n) {
            const int col = n0 + wc * 64 + n * 16 + fr;
#pragma unroll
            for (int r = 0; r < 4; ++r) {
                const int row = m0 + wr * 128 + m * 16 + ksl * 4 + r;
                const size_t idx = (size_t)row * N + col;
                const float v = acc[m][n][r];
                if (EPI == 0) {
                    ((__hip_bfloat16*)Cv)[idx] = __float2bfloat16(v);
                } else if (EPI == 1) {
                    ((__hip_bfloat16*)Cv)[idx] = __float2bfloat16(v + bias[col]);
                } else {
                    ((float*)Cv)[idx] = resid[idx] + v + bias[col];
                }
            }
        }
    }
}

// ---------------------------------------------------------------------------
// Axial attention. One block (256 thr) per (group, self/cross).
// qkv: [N0,2048] = [q_self | k_self | v_self | q_cross]
// kvc: [N1,1024] = [k_cross | v_cross]
// Output: oc[token*ldo + (cross?cross_off:0) + c], c in [0,512)
// ---------------------------------------------------------------------------
__global__ __launch_bounds__(256)
void attn_kernel(const __hip_bfloat16* __restrict__ qkv,
                 const __hip_bfloat16* __restrict__ kvc,
                 __hip_bfloat16* __restrict__ oc, int ldo, int cross_off,
                 int ip)
{
    __shared__ __align__(16) __hip_bfloat16 Qs[12][520];
    __shared__ __align__(16) __hip_bfloat16 Ks[12][520];
    __shared__ __align__(16) __hip_bfloat16 Vs[12][520];
    __shared__ float P[8][12][12];

    const int g = blockIdx.x;
    const bool cross = blockIdx.y != 0;
    const int tid = threadIdx.x;

    const int b  = g / 144;
    const int r1 = (g % 144) / 12;
    const int r2 = g % 12;
    int n_base, qstride, kvb, kvstride, tk;
    if (ip == 0) {          // attend over T
        n_base = b * 1728 + r1 * 12 + r2; qstride = 144;
        kvb = b * 432 + (r1 >> 1) * 6 + (r2 >> 1); kvstride = 36; tk = 12;
    } else if (ip == 1) {   // attend over LA
        n_base = b * 1728 + r1 * 144 + r2; qstride = 12;
        kvb = b * 432 + r1 * 36 + (r2 >> 1); kvstride = 6; tk = 6;
    } else {                // attend over LO
        n_base = b * 1728 + r1 * 144 + r2 * 12; qstride = 1;
        kvb = b * 432 + r1 * 36 + (r2 >> 1) * 6; kvstride = 1; tk = 6;
    }
    if (!cross) tk = 12;

    // ---- stage Q (12 rows x 512 bf16 = 64 uint4 per row)
    const int qoff = cross ? 1536 : 0;
    for (int idx = tid; idx < 12 * 64; idx += 256) {
        const int i = idx >> 6, c = idx & 63;
        const uint4* src = (const uint4*)(qkv + (size_t)(n_base + i * qstride) * 2048 + qoff);
        *(uint4*)(&Qs[i][c * 8]) = src[c];
    }
    // ---- stage K/V
    if (!cross) {
        for (int idx = tid; idx < 12 * 64; idx += 256) {
            const int j = idx >> 6, c = idx & 63;
            const __hip_bfloat16* row = qkv + (size_t)(n_base + j * qstride) * 2048;
            *(uint4*)(&Ks[j][c * 8]) = ((const uint4*)(row + 512))[c];
            *(uint4*)(&Vs[j][c * 8]) = ((const uint4*)(row + 1024))[c];
        }
    } else {
        for (int idx = tid; idx < tk * 64; idx += 256) {
            const int j = idx >> 6, c = idx & 63;
            const __hip_bfloat16* row = kvc + (size_t)(kvb + j * kvstride) * 1024;
            *(uint4*)(&Ks[j][c * 8]) = ((const uint4*)(row))[c];
            *(uint4*)(&Vs[j][c * 8]) = ((const uint4*)(row + 512))[c];
        }
    }
    __syncthreads();

    // ---- dots: P[h][i][j] = (q_i . k_j) * E^-0.5
    const int ndots = 8 * 12 * tk;
    for (int idx = tid; idx < ndots; idx += 256) {
        const int h = idx / (12 * tk);
        const int rem = idx % (12 * tk);
        const int i = rem / tk, j = rem % tk;
        const __hip_bfloat162* q2 = (const __hip_bfloat162*)(&Qs[i][h * 64]);
        const __hip_bfloat162* k2 = (const __hip_bfloat162*)(&Ks[j][h * 64]);
        float s = 0.f;
#pragma unroll
        for (int e = 0; e < 32; ++e) {
            const float2 qf = __bfloat1622float2(q2[e]);
            const float2 kf = __bfloat1622float2(k2[e]);
            s += qf.x * kf.x + qf.y * kf.y;
        }
        P[h][i][j] = s * 0.125f;
    }
    __syncthreads();

    // ---- softmax over j
    if (tid < 96) {
        const int h = tid / 12, i = tid % 12;
        float mx = -1e30f;
        for (int j = 0; j < tk; ++j) mx = fmaxf(mx, P[h][i][j]);
        float sum = 0.f;
        for (int j = 0; j < tk; ++j) { const float e = __expf(P[h][i][j] - mx); P[h][i][j] = e; sum += e; }
        const float inv = 1.f / sum;
        for (int j = 0; j < tk; ++j) P[h][i][j] *= inv;
    }
    __syncthreads();

    // ---- out: o[i][c] = sum_j P[h][i][j] * V[j][c]
    for (int idx = tid; idx < 12 * 512; idx += 256) {
        const int i = idx >> 9, c = idx & 511;
        const int h = c >> 6;
        float a = 0.f;
        for (int j = 0; j < tk; ++j)
            a += P[h][i][j] * __bfloat162float(Vs[j][c]);
        oc[(size_t)(n_base + i * qstride) * ldo + (cross ? cross_off : 0) + c] = __float2bfloat16(a);
    }
}

// ---------------------------------------------------------------------------
extern "C" void kernel_launch(void* const* d_in, const int* in_sizes, int n_in,
                              void* d_out, int out_size, void* d_ws, size_t ws_size,
                              hipStream_t stream)
{
    (void)in_sizes; (void)n_in; (void)out_size; (void)ws_size;
    const float* x0        = (const float*)d_in[0];
    const float* x1        = (const float*)d_in[1];
    const float* wq_self   = (const float*)d_in[2];
    const float* wkv_self  = (const float*)d_in[3];
    const float* wq_cross  = (const float*)d_in[4];
    const float* wkv_cross = (const float*)d_in[5];
    const float* w_out     = (const float*)d_in[6];
    const float* b_out     = (const float*)d_in[7];

    // d_out doubles as the qkv scratch: 55296*2048*2 B == out_size*4 B exactly
    __hip_bfloat16* qkv = (__hip_bfloat16*)d_out;

    char* ws = (char*)d_ws;
    size_t off = 0;
    auto alloc = [&](size_t bytes) {
        void* p = ws + off;
        off += (bytes + 255) & ~(size_t)255;
        return p;
    };
    __hip_bfloat16* f0  = (__hip_bfloat16*)alloc((size_t)N0 * 1024 * 2);
    __hip_bfloat16* f1  = (__hip_bfloat16*)alloc((size_t)N1 * 512 * 2);
    __hip_bfloat16* kvc = (__hip_bfloat16*)alloc((size_t)N1 * 1024 * 2);
    __hip_bfloat16* W1t = (__hip_bfloat16*)alloc((size_t)3 * 2048 * 1024 * 2);
    __hip_bfloat16* W2t = (__hip_bfloat16*)alloc((size_t)3 * 1024 * 512 * 2);
    __hip_bfloat16* W3t = (__hip_bfloat16*)alloc((size_t)3 * 1024 * 1024 * 2);

    // layernorms
    ln_kernel<1024><<<N0, 256, 0, stream>>>(x0, f0);
    ln_kernel<512><<<N1, 256, 0, stream>>>(x1, f1);

    // weight transposes into B^T (bf16)
    for (int ip = 0; ip < 3; ++ip) {
        transpose_kernel<<<dim3(16, 32), 256, 0, stream>>>(
            wq_self + (size_t)ip * 1024 * 512, W1t + (size_t)ip * 2048 * 1024, 1024, 512);
        transpose_kernel<<<dim3(32, 32), 256, 0, stream>>>(
            wkv_self + (size_t)ip * 1024 * 1024, W1t + (size_t)ip * 2048 * 1024 + (size_t)512 * 1024, 1024, 1024);
        transpose_kernel<<<dim3(16, 32), 256, 0, stream>>>(
            wq_cross + (size_t)ip * 1024 * 512, W1t + (size_t)ip * 2048 * 1024 + (size_t)1536 * 1024, 1024, 512);
        transpose_kernel<<<dim3(32, 16), 256, 0, stream>>>(
            wkv_cross + (size_t)ip * 512 * 1024, W2t + (size_t)ip * 1024 * 512, 512, 1024);
        transpose_kernel<<<dim3(32, 32), 256, 0, stream>>>(
            w_out + (size_t)ip * 1024 * 1024, W3t + (size_t)ip * 1024 * 1024, 1024, 1024);
    }

    // 3 axial layers
    for (int ip = 0; ip < 3; ++ip) {
        // fused qkv projection: [N0,1024] @ [1024,2048] -> d_out (grid 8x216)
        gemm8p<0, false><<<dim3(8, 216), 512, 0, stream>>>(
            f0, W1t + (size_t)ip * 2048 * 1024, qkv, nullptr, nullptr, N0, 2048, 1024, 1024);
        // cross kv projection: [N1,512] @ [512,1024] -> kvc (grid 4x54)
        gemm8p<0, false><<<dim3(4, 54), 512, 0, stream>>>(
            f1, W2t + (size_t)ip * 1024 * 512, kvc, nullptr, nullptr, N1, 1024, 512, 512);
        if (ip < 2) {
            // attention writes o_self -> qkv[:,0:512], o_cross -> qkv[:,1536:2048]
            attn_kernel<<<dim3(4608, 2), 256, 0, stream>>>(qkv, kvc, qkv, 2048, 1536, ip);
            // out-proj with split-A read, writes new f0 (bf16 + bias)
            gemm8p<1, true><<<dim3(4, 216), 512, 0, stream>>>(
                qkv, W3t + (size_t)ip * 1024 * 1024, f0, b_out + ip * 1024, nullptr,
                N0, 1024, 1024, 2048);
        } else {
            // attention writes [o_self|o_cross] into f0 (dead here)
            attn_kernel<<<dim3(4608, 2), 256, 0, stream>>>(qkv, kvc, f0, 1024, 512, ip);
            // final out-proj: f0 @ W3t + bias + x0 -> d_out (fp32)
            gemm8p<2, false><<<dim3(4, 216), 512, 0, stream>>>(
                f0, W3t + (size_t)ip * 1024 * 1024, d_out, b_out + ip * 1024, x0,
                N0, 1024, 1024, 1024);
        }
    }
}

// Round 4
// 1861.290 us; speedup vs baseline: 1.2906x; 1.0049x over previous
//
#include <hip/hip_runtime.h>
#include <hip/hip_bf16.h>

// ---------------------------------------------------------------------------
// MultiFieldAxialAttention on MI355X (gfx950)
// B=32, T=12, LA=12, LO=12, D0=1024, D1=512, H=8+8, E=64
// GEMMs: 256x256x64 8-phase counted-vmcnt template (T1+T2+T3+T4+T5)
// ---------------------------------------------------------------------------

typedef __bf16 bf16x8 __attribute__((ext_vector_type(8)));
typedef float floatx4 __attribute__((ext_vector_type(4)));

#define N0 55296   // 32*12*12*12 tokens of field0
#define N1 13824   // 32*12*6*6 tokens of field1

#define RAW_BARRIER() asm volatile("s_barrier" ::: "memory")
#define VMCNT(n) asm volatile("s_waitcnt vmcnt(" #n ")" ::: "memory")

__device__ __forceinline__ void gload16(const void* g, void* l) {
    __builtin_amdgcn_global_load_lds(
        (const __attribute__((address_space(1))) unsigned int*)g,
        (__attribute__((address_space(3))) unsigned int*)l, 16, 0, 0);
}

// ---------------------------------------------------------------------------
// LayerNorm (elementwise_affine=False): fp32 in -> bf16 out, 1 block per row.
// Single launch: rows [0,N0) -> x0/f0 (D=1024), rows [N0,N0+N1) -> x1/f1 (D=512)
// ---------------------------------------------------------------------------
template <int D>
__device__ __forceinline__ void ln_body(const float* __restrict__ xr,
                                        __hip_bfloat16* __restrict__ yr)
{
    const int tid = threadIdx.x;
    float vals[D / 256];
    float s = 0.f, q = 0.f;
#pragma unroll
    for (int k = 0; k < D / 256; ++k) {
        float v = xr[tid + k * 256];
        vals[k] = v; s += v; q += v * v;
    }
#pragma unroll
    for (int off = 32; off > 0; off >>= 1) {
        s += __shfl_xor(s, off);
        q += __shfl_xor(q, off);
    }
    __shared__ float rs[4], rq[4];
    const int w = tid >> 6;
    if ((tid & 63) == 0) { rs[w] = s; rq[w] = q; }
    __syncthreads();
    s = rs[0] + rs[1] + rs[2] + rs[3];
    q = rq[0] + rq[1] + rq[2] + rq[3];
    const float mean = s * (1.f / D);
    const float var  = q * (1.f / D) - mean * mean;
    const float rstd = rsqrtf(var + 1e-5f);
#pragma unroll
    for (int k = 0; k < D / 256; ++k)
        yr[tid + k * 256] = __float2bfloat16((vals[k] - mean) * rstd);
}

__global__ __launch_bounds__(256)
void ln_all(const float* __restrict__ x0, const float* __restrict__ x1,
            __hip_bfloat16* __restrict__ f0, __hip_bfloat16* __restrict__ f1)
{
    const int row = blockIdx.x;
    if (row < N0) {
        ln_body<1024>(x0 + (size_t)row * 1024, f0 + (size_t)row * 1024);
    } else {
        const int r = row - N0;
        ln_body<512>(x1 + (size_t)r * 512, f1 + (size_t)r * 512);
    }
}

// ---------------------------------------------------------------------------
// All 15 weight transposes in ONE launch. in [K][N] fp32 -> out [N][K] bf16.
// Flat grid of 32x32 tiles; segments:
//   [0,1536)      wq_self   3x(1024x512)  -> W1t + ip*2M + 0        (ld 1024)
//   [1536,4608)   wkv_self  3x(1024x1024) -> W1t + ip*2M + 512K     (ld 1024)
//   [4608,6144)   wq_cross  3x(1024x512)  -> W1t + ip*2M + 1536K    (ld 1024)
//   [6144,7680)   wkv_cross 3x(512x1024)  -> W2t + ip*512K          (ld 512)
//   [7680,10752)  w_out     3x(1024x1024) -> W3t + ip*1M            (ld 1024)
// ---------------------------------------------------------------------------
__global__ __launch_bounds__(256)
void transpose_all(const float* __restrict__ wqs, const float* __restrict__ wkvs,
                   const float* __restrict__ wqc, const float* __restrict__ wkvc,
                   const float* __restrict__ wo,
                   __hip_bfloat16* __restrict__ W1t,
                   __hip_bfloat16* __restrict__ W2t,
                   __hip_bfloat16* __restrict__ W3t)
{
    int idx = blockIdx.x;
    const float* src;
    __hip_bfloat16* dst;
    int K, N;
    if (idx < 1536) {
        const int ip = idx / 512; idx %= 512; K = 1024; N = 512;
        src = wqs + (size_t)ip * 524288;  dst = W1t + (size_t)ip * 2097152;
    } else if (idx < 4608) {
        idx -= 1536;
        const int ip = idx / 1024; idx %= 1024; K = 1024; N = 1024;
        src = wkvs + (size_t)ip * 1048576; dst = W1t + (size_t)ip * 2097152 + 524288;
    } else if (idx < 6144) {
        idx -= 4608;
        const int ip = idx / 512; idx %= 512; K = 1024; N = 512;
        src = wqc + (size_t)ip * 524288;  dst = W1t + (size_t)ip * 2097152 + 1572864;
    } else if (idx < 7680) {
        idx -= 6144;
        const int ip = idx / 512; idx %= 512; K = 512; N = 1024;
        src = wkvc + (size_t)ip * 524288; dst = W2t + (size_t)ip * 524288;
    } else {
        idx -= 7680;
        const int ip = idx / 1024; idx %= 1024; K = 1024; N = 1024;
        src = wo + (size_t)ip * 1048576;  dst = W3t + (size_t)ip * 1048576;
    }
    const int tiles_x = N >> 5;
    const int n0 = (idx % tiles_x) * 32, k0 = (idx / tiles_x) * 32;

    __shared__ float tile[32][33];
    const int tx = threadIdx.x & 31, ty = threadIdx.x >> 5; // 32 x 8
#pragma unroll
    for (int d = 0; d < 4; ++d)
        tile[ty + d * 8][tx] = src[(size_t)(k0 + ty + d * 8) * N + n0 + tx];
    __syncthreads();
#pragma unroll
    for (int d = 0; d < 4; ++d)
        dst[(size_t)(n0 + ty + d * 8) * K + k0 + tx] = __float2bfloat16(tile[tx][ty + d * 8]);
}

// ---------------------------------------------------------------------------
// 256x256 8-phase bf16 MFMA GEMM: C[M,N] = A[M,K] @ Bt[N,K]^T
// 512 thr = 8 waves (2 Mx4 N), per-wave 128x64 out, BK=64, dbuf LDS 128 KiB.
// 4 phases per K-tile; FIFO prefetch A0,B0,A1,B1 one tile ahead; uniform
// s_waitcnt vmcnt(4) keeps 2 half-tiles in flight. Last iteration stages a
// dummy k=0 tile into the dead buffer (drained by vmcnt(0) before epilogue)
// so the tail needs no extra barrier structure.
// XOR swizzle (row&7) on 16B col-groups: pre-swizzled global src + swizzled
// ds_read (rule 21); measured 0 bank conflicts.
// ASPLIT: logical k<512 -> phys col k ; k>=512 -> col k+1024 (lda=2048)
// EPI: 0 = bf16 ; 1 = bf16 + bias ; 2 = fp32 + bias + resid
// ---------------------------------------------------------------------------
template <int EPI, bool ASPLIT>
__global__ __launch_bounds__(512)
void gemm8p(const __hip_bfloat16* __restrict__ A,
            const __hip_bfloat16* __restrict__ Bt,
            void* __restrict__ Cv,
            const float* __restrict__ bias,
            const float* __restrict__ resid,
            int M, int N, int K, int lda)
{
    __shared__ __align__(16) char lds[131072];

    // bijective XCD swizzle (all grids are multiples of 8 workgroups)
    const int gx  = gridDim.x;
    const int nwg = gx * gridDim.y;
    const int bid = blockIdx.y * gx + blockIdx.x;
    const int swz = (bid & 7) * (nwg >> 3) + (bid >> 3);
    const int m0 = (swz / gx) * 256;
    const int n0 = (swz % gx) * 256;

    const int t    = threadIdx.x;
    const int w    = t >> 6;
    const int lane = t & 63;
    const int wr   = w >> 2;     // 0..1  (M half)
    const int wc   = w & 3;      // 0..3  (N quarter)
    const int fr   = lane & 15;
    const int ksl  = lane >> 4;

    floatx4 acc[8][4] = {};

    // ---- staging source bases (pre-swizzled col: key = local row & 7)
    const int tr   = t >> 3;                      // 0..63
    const int scol = ((t & 7) ^ (tr & 7)) << 3;
    const __hip_bfloat16* aG = A  + (size_t)(m0 + tr) * lda + scol;
    const __hip_bfloat16* bG = Bt + (size_t)(n0 + ((tr >> 5) * 64) + (tr & 31)) * K + scol;
    const int ldst = t * 16;                      // linear LDS dest

    // ---- ds_read per-thread base offsets (kk=1 via ^64)
    const int cg0 = ksl ^ (fr & 7);
    const int aO0 = (wr * 64 + fr) * 128 + cg0 * 16;
    const int bO0 = (wc * 32 + fr) * 128 + cg0 * 16;

    // LDS map per buffer (65536 B): A-h0 @0, A-h1 @16384, B-h0 @32768, B-h1 @49152
    auto stageA = [&](char* buf, int h, int ka) {
        gload16(aG + ka + (size_t)(h * 64)       * lda, buf + h * 16384 + ldst);
        gload16(aG + ka + (size_t)(h * 64 + 128) * lda, buf + h * 16384 + 8192 + ldst);
    };
    auto stageB = [&](char* buf, int h, int kb) {
        gload16(bG + kb + (size_t)(h * 32)       * K, buf + 32768 + h * 16384 + ldst);
        gload16(bG + kb + (size_t)(h * 32 + 128) * K, buf + 32768 + h * 16384 + 8192 + ldst);
    };

    const char* bufC = lds;
    auto ldA = [&](int h, bf16x8 (&a)[2][4]) {
#pragma unroll
        for (int mm = 0; mm < 4; ++mm) {
            a[0][mm] = *(const bf16x8*)(bufC + h * 16384 + mm * 2048 + aO0);
            a[1][mm] = *(const bf16x8*)(bufC + h * 16384 + mm * 2048 + (aO0 ^ 64));
        }
    };
    auto ldB = [&](int h, bf16x8 (&b)[2][2]) {
#pragma unroll
        for (int nn = 0; nn < 2; ++nn) {
            b[0][nn] = *(const bf16x8*)(bufC + 32768 + h * 16384 + nn * 2048 + bO0);
            b[1][nn] = *(const bf16x8*)(bufC + 32768 + h * 16384 + nn * 2048 + (bO0 ^ 64));
        }
    };
    auto quad = [&](bf16x8 (&a)[2][4], bf16x8 (&b)[2][2], int mlo, int nlo) {
        __builtin_amdgcn_s_setprio(1);
#pragma unroll
        for (int kk = 0; kk < 2; ++kk)
#pragma unroll
            for (int mm = 0; mm < 4; ++mm)
#pragma unroll
                for (int nn = 0; nn < 2; ++nn)
                    acc[mlo + mm][nlo + nn] = __builtin_amdgcn_mfma_f32_16x16x32_bf16(
                        a[kk][mm], b[kk][nn], acc[mlo + mm][nlo + nn], 0, 0, 0);
        __builtin_amdgcn_s_setprio(0);
    };

    const int NT = K >> 6;

    // prologue: tile 0 -> buf0, FIFO order A0,B0,A1,B1
    stageA(lds, 0, 0);
    stageB(lds, 0, 0);
    stageA(lds, 1, 0);
    stageB(lds, 1, 0);
    VMCNT(4);
    RAW_BARRIER();

    bf16x8 a0[2][4], a1[2][4], b0[2][2], b1[2][2];

    for (int tt = 0; tt < NT; ++tt) {
        bufC = lds + ((tt & 1) << 16);
        char* bufN = lds + (((tt + 1) & 1) << 16);
        // last iter: dummy-stage k=0 (in-bounds, dead buffer) to keep the
        // vmcnt FIFO arithmetic identical in every iteration
        const int kc = (tt == NT - 1) ? 0 : (tt + 1) << 6;
        const int ka = ASPLIT ? (kc >= 512 ? kc + 1024 : kc) : kc;
        // P0: read A-h0,B-h0(tt); prefetch A-h0(next); MFMA quad(m0-3, n0-1)
        ldA(0, a0); ldB(0, b0);
        stageA(bufN, 0, ka);
        RAW_BARRIER(); __builtin_amdgcn_sched_barrier(0);
        quad(a0, b0, 0, 0);
        VMCNT(4); RAW_BARRIER();
        // P1: read A-h1(tt); prefetch B-h0(next); MFMA quad(m4-7, n0-1)
        ldA(1, a1);
        stageB(bufN, 0, kc);
        RAW_BARRIER(); __builtin_amdgcn_sched_barrier(0);
        quad(a1, b0, 4, 0);
        VMCNT(4); RAW_BARRIER();
        // P2: read B-h1(tt); prefetch A-h1(next); MFMA quad(m0-3, n2-3)
        ldB(1, b1);
        stageA(bufN, 1, ka);
        RAW_BARRIER(); __builtin_amdgcn_sched_barrier(0);
        quad(a0, b1, 0, 2);
        RAW_BARRIER();
        // P3: prefetch B-h1(next); MFMA quad(m4-7, n2-3)
        stageB(bufN, 1, kc);
        RAW_BARRIER(); __builtin_amdgcn_sched_barrier(0);
        quad(a1, b1, 4, 2);
        VMCNT(4); RAW_BARRIER();
    }
    VMCNT(0);   // drain dummy stages before endpgm

    // ---- epilogue
#pragma unroll
    for (int m = 0; m < 8; ++m) {
#pragma unroll
        for (int n = 0; n < 4; ++n) {
            const int col = n0 + wc * 64 + n * 16 + fr;
#pragma unroll
            for (int r = 0; r < 4; ++r) {
                const int row = m0 + wr * 128 + m * 16 + ksl * 4 + r;
                const size_t idx = (size_t)row * N + col;
                const float v = acc[m][n][r];
                if (EPI == 0) {
                    ((__hip_bfloat16*)Cv)[idx] = __float2bfloat16(v);
                } else if (EPI == 1) {
                    ((__hip_bfloat16*)Cv)[idx] = __float2bfloat16(v + bias[col]);
                } else {
                    ((float*)Cv)[idx] = resid[idx] + v + bias[col];
                }
            }
        }
    }
}

// ---------------------------------------------------------------------------
// Axial attention. One block (256 thr) per (group, self/cross).
// qkv: [N0,2048] = [q_self | k_self | v_self | q_cross]
// kvc: [N1,1024] = [k_cross | v_cross]
// Output: oc[token*ldo + (cross?cross_off:0) + c], c in [0,512)
// ---------------------------------------------------------------------------
__global__ __launch_bounds__(256)
void attn_kernel(const __hip_bfloat16* __restrict__ qkv,
                 const __hip_bfloat16* __restrict__ kvc,
                 __hip_bfloat16* __restrict__ oc, int ldo, int cross_off,
                 int ip)
{
    __shared__ __align__(16) __hip_bfloat16 Qs[12][520];
    __shared__ __align__(16) __hip_bfloat16 Ks[12][520];
    __shared__ __align__(16) __hip_bfloat16 Vs[12][520];
    __shared__ float P[8][12][12];

    const int g = blockIdx.x;
    const bool cross = blockIdx.y != 0;
    const int tid = threadIdx.x;

    const int b  = g / 144;
    const int r1 = (g % 144) / 12;
    const int r2 = g % 12;
    int n_base, qstride, kvb, kvstride, tk;
    if (ip == 0) {          // attend over T
        n_base = b * 1728 + r1 * 12 + r2; qstride = 144;
        kvb = b * 432 + (r1 >> 1) * 6 + (r2 >> 1); kvstride = 36; tk = 12;
    } else if (ip == 1) {   // attend over LA
        n_base = b * 1728 + r1 * 144 + r2; qstride = 12;
        kvb = b * 432 + r1 * 36 + (r2 >> 1); kvstride = 6; tk = 6;
    } else {                // attend over LO
        n_base = b * 1728 + r1 * 144 + r2 * 12; qstride = 1;
        kvb = b * 432 + r1 * 36 + (r2 >> 1) * 6; kvstride = 1; tk = 6;
    }
    if (!cross) tk = 12;

    // ---- stage Q (12 rows x 512 bf16 = 64 uint4 per row)
    const int qoff = cross ? 1536 : 0;
    for (int idx = tid; idx < 12 * 64; idx += 256) {
        const int i = idx >> 6, c = idx & 63;
        const uint4* src = (const uint4*)(qkv + (size_t)(n_base + i * qstride) * 2048 + qoff);
        *(uint4*)(&Qs[i][c * 8]) = src[c];
    }
    // ---- stage K/V
    if (!cross) {
        for (int idx = tid; idx < 12 * 64; idx += 256) {
            const int j = idx >> 6, c = idx & 63;
            const __hip_bfloat16* row = qkv + (size_t)(n_base + j * qstride) * 2048;
            *(uint4*)(&Ks[j][c * 8]) = ((const uint4*)(row + 512))[c];
            *(uint4*)(&Vs[j][c * 8]) = ((const uint4*)(row + 1024))[c];
        }
    } else {
        for (int idx = tid; idx < tk * 64; idx += 256) {
            const int j = idx >> 6, c = idx & 63;
            const __hip_bfloat16* row = kvc + (size_t)(kvb + j * kvstride) * 1024;
            *(uint4*)(&Ks[j][c * 8]) = ((const uint4*)(row))[c];
            *(uint4*)(&Vs[j][c * 8]) = ((const uint4*)(row + 512))[c];
        }
    }
    __syncthreads();

    // ---- dots: P[h][i][j] = (q_i . k_j) * E^-0.5
    const int ndots = 8 * 12 * tk;
    for (int idx = tid; idx < ndots; idx += 256) {
        const int h = idx / (12 * tk);
        const int rem = idx % (12 * tk);
        const int i = rem / tk, j = rem % tk;
        const __hip_bfloat162* q2 = (const __hip_bfloat162*)(&Qs[i][h * 64]);
        const __hip_bfloat162* k2 = (const __hip_bfloat162*)(&Ks[j][h * 64]);
        float s = 0.f;
#pragma unroll
        for (int e = 0; e < 32; ++e) {
            const float2 qf = __bfloat1622float2(q2[e]);
            const float2 kf = __bfloat1622float2(k2[e]);
            s += qf.x * kf.x + qf.y * kf.y;
        }
        P[h][i][j] = s * 0.125f;
    }
    __syncthreads();

    // ---- softmax over j
    if (tid < 96) {
        const int h = tid / 12, i = tid % 12;
        float mx = -1e30f;
        for (int j = 0; j < tk; ++j) mx = fmaxf(mx, P[h][i][j]);
        float sum = 0.f;
        for (int j = 0; j < tk; ++j) { const float e = __expf(P[h][i][j] - mx); P[h][i][j] = e; sum += e; }
        const float inv = 1.f / sum;
        for (int j = 0; j < tk; ++j) P[h][i][j] *= inv;
    }
    __syncthreads();

    // ---- out: o[i][c] = sum_j P[h][i][j] * V[j][c]
    for (int idx = tid; idx < 12 * 512; idx += 256) {
        const int i = idx >> 9, c = idx & 511;
        const int h = c >> 6;
        float a = 0.f;
        for (int j = 0; j < tk; ++j)
            a += P[h][i][j] * __bfloat162float(Vs[j][c]);
        oc[(size_t)(n_base + i * qstride) * ldo + (cross ? cross_off : 0) + c] = __float2bfloat16(a);
    }
}

// ---------------------------------------------------------------------------
extern "C" void kernel_launch(void* const* d_in, const int* in_sizes, int n_in,
                              void* d_out, int out_size, void* d_ws, size_t ws_size,
                              hipStream_t stream)
{
    (void)in_sizes; (void)n_in; (void)out_size; (void)ws_size;
    const float* x0        = (const float*)d_in[0];
    const float* x1        = (const float*)d_in[1];
    const float* wq_self   = (const float*)d_in[2];
    const float* wkv_self  = (const float*)d_in[3];
    const float* wq_cross  = (const float*)d_in[4];
    const float* wkv_cross = (const float*)d_in[5];
    const float* w_out     = (const float*)d_in[6];
    const float* b_out     = (const float*)d_in[7];

    // d_out doubles as the qkv scratch: 55296*2048*2 B == out_size*4 B exactly
    __hip_bfloat16* qkv = (__hip_bfloat16*)d_out;

    char* ws = (char*)d_ws;
    size_t off = 0;
    auto alloc = [&](size_t bytes) {
        void* p = ws + off;
        off += (bytes + 255) & ~(size_t)255;
        return p;
    };
    __hip_bfloat16* f0  = (__hip_bfloat16*)alloc((size_t)N0 * 1024 * 2);
    __hip_bfloat16* f1  = (__hip_bfloat16*)alloc((size_t)N1 * 512 * 2);
    __hip_bfloat16* kvc = (__hip_bfloat16*)alloc((size_t)N1 * 1024 * 2);
    __hip_bfloat16* W1t = (__hip_bfloat16*)alloc((size_t)3 * 2048 * 1024 * 2);
    __hip_bfloat16* W2t = (__hip_bfloat16*)alloc((size_t)3 * 1024 * 512 * 2);
    __hip_bfloat16* W3t = (__hip_bfloat16*)alloc((size_t)3 * 1024 * 1024 * 2);
    alloc(256);  // guard pad

    // layernorms (1 launch) + all weight transposes (1 launch)
    ln_all<<<N0 + N1, 256, 0, stream>>>(x0, x1, f0, f1);
    transpose_all<<<10752, 256, 0, stream>>>(wq_self, wkv_self, wq_cross,
                                             wkv_cross, w_out, W1t, W2t, W3t);

    // 3 axial layers
    for (int ip = 0; ip < 3; ++ip) {
        // fused qkv projection: [N0,1024] @ [1024,2048] -> d_out (grid 8x216)
        gemm8p<0, false><<<dim3(8, 216), 512, 0, stream>>>(
            f0, W1t + (size_t)ip * 2048 * 1024, qkv, nullptr, nullptr, N0, 2048, 1024, 1024);
        // cross kv projection: [N1,512] @ [512,1024] -> kvc (grid 4x54)
        gemm8p<0, false><<<dim3(4, 54), 512, 0, stream>>>(
            f1, W2t + (size_t)ip * 1024 * 512, kvc, nullptr, nullptr, N1, 1024, 512, 512);
        if (ip < 2) {
            // attention writes o_self -> qkv[:,0:512], o_cross -> qkv[:,1536:2048]
            attn_kernel<<<dim3(4608, 2), 256, 0, stream>>>(qkv, kvc, qkv, 2048, 1536, ip);
            // out-proj with split-A read, writes new f0 (bf16 + bias)
            gemm8p<1, true><<<dim3(4, 216), 512, 0, stream>>>(
                qkv, W3t + (size_t)ip * 1024 * 1024, f0, b_out + ip * 1024, nullptr,
                N0, 1024, 1024, 2048);
        } else {
            // attention writes [o_self|o_cross] into f0 (dead here)
            attn_kernel<<<dim3(4608, 2), 256, 0, stream>>>(qkv, kvc, f0, 1024, 512, ip);
            // final out-proj: f0 @ W3t + bias + x0 -> d_out (fp32)
            gemm8p<2, false><<<dim3(4, 216), 512, 0, stream>>>(
                f0, W3t + (size_t)ip * 1024 * 1024, d_out, b_out + ip * 1024, x0,
                N0, 1024, 1024, 1024);
        }
    }
}

// Round 5
// 1739.522 us; speedup vs baseline: 1.3810x; 1.0700x over previous
//
#include <hip/hip_runtime.h>
#include <hip/hip_bf16.h>

// ---------------------------------------------------------------------------
// MultiFieldAxialAttention on MI355X (gfx950)
// B=32, T=12, LA=12, LO=12, D0=1024, D1=512, H=8+8, E=64
//
// Key algebraic fold: no nonlinearity between out-proj and next qkv-proj
// (layernorm applied once before the loop), so
//   qkv_{ip+1} = concat_ip @ (W3[ip] @ W1[ip+1]) + b[ip] @ W1[ip+1]
// -> the two intermediate out-projection GEMMs disappear.
// All 3 cross-KV projections depend only on static f1 -> one N=3072 GEMM.
//
// Dataflow per layer: GEMM reads f0 -> writes qkv(d_out); attn reads
// qkv+kvc3 -> writes concat to f0. Final: f0 @ W3t[2] + b[2] + x0 -> d_out.
// ---------------------------------------------------------------------------

typedef __bf16 bf16x8 __attribute__((ext_vector_type(8)));
typedef float floatx4 __attribute__((ext_vector_type(4)));

#define N0 55296   // 32*12*12*12 tokens of field0
#define N1 13824   // 32*12*6*6 tokens of field1

#define RAW_BARRIER() asm volatile("s_barrier" ::: "memory")
#define VMCNT(n) asm volatile("s_waitcnt vmcnt(" #n ")" ::: "memory")

__device__ __forceinline__ void gload16(const void* g, void* l) {
    __builtin_amdgcn_global_load_lds(
        (const __attribute__((address_space(1))) unsigned int*)g,
        (__attribute__((address_space(3))) unsigned int*)l, 16, 0, 0);
}

// ---------------------------------------------------------------------------
// LayerNorm: fp32 in -> bf16 out, 1 block per row; single launch for x0+x1
// ---------------------------------------------------------------------------
template <int D>
__device__ __forceinline__ void ln_body(const float* __restrict__ xr,
                                        __hip_bfloat16* __restrict__ yr)
{
    const int tid = threadIdx.x;
    float vals[D / 256];
    float s = 0.f, q = 0.f;
#pragma unroll
    for (int k = 0; k < D / 256; ++k) {
        float v = xr[tid + k * 256];
        vals[k] = v; s += v; q += v * v;
    }
#pragma unroll
    for (int off = 32; off > 0; off >>= 1) {
        s += __shfl_xor(s, off);
        q += __shfl_xor(q, off);
    }
    __shared__ float rs[4], rq[4];
    const int w = tid >> 6;
    if ((tid & 63) == 0) { rs[w] = s; rq[w] = q; }
    __syncthreads();
    s = rs[0] + rs[1] + rs[2] + rs[3];
    q = rq[0] + rq[1] + rq[2] + rq[3];
    const float mean = s * (1.f / D);
    const float var  = q * (1.f / D) - mean * mean;
    const float rstd = rsqrtf(var + 1e-5f);
#pragma unroll
    for (int k = 0; k < D / 256; ++k)
        yr[tid + k * 256] = __float2bfloat16((vals[k] - mean) * rstd);
}

__global__ __launch_bounds__(256)
void ln_all(const float* __restrict__ x0, const float* __restrict__ x1,
            __hip_bfloat16* __restrict__ f0, __hip_bfloat16* __restrict__ f1)
{
    const int row = blockIdx.x;
    if (row < N0) {
        ln_body<1024>(x0 + (size_t)row * 1024, f0 + (size_t)row * 1024);
    } else {
        const int r = row - N0;
        ln_body<512>(x1 + (size_t)r * 512, f1 + (size_t)r * 512);
    }
}

// ---------------------------------------------------------------------------
// All 15 weight transposes in ONE launch. in [K][N] fp32 -> out [N][K] bf16.
// ---------------------------------------------------------------------------
__global__ __launch_bounds__(256)
void transpose_all(const float* __restrict__ wqs, const float* __restrict__ wkvs,
                   const float* __restrict__ wqc, const float* __restrict__ wkvc,
                   const float* __restrict__ wo,
                   __hip_bfloat16* __restrict__ W1t,
                   __hip_bfloat16* __restrict__ W2t,
                   __hip_bfloat16* __restrict__ W3t)
{
    int idx = blockIdx.x;
    const float* src;
    __hip_bfloat16* dst;
    int K, N;
    if (idx < 1536) {
        const int ip = idx / 512; idx %= 512; K = 1024; N = 512;
        src = wqs + (size_t)ip * 524288;  dst = W1t + (size_t)ip * 2097152;
    } else if (idx < 4608) {
        idx -= 1536;
        const int ip = idx / 1024; idx %= 1024; K = 1024; N = 1024;
        src = wkvs + (size_t)ip * 1048576; dst = W1t + (size_t)ip * 2097152 + 524288;
    } else if (idx < 6144) {
        idx -= 4608;
        const int ip = idx / 512; idx %= 512; K = 1024; N = 512;
        src = wqc + (size_t)ip * 524288;  dst = W1t + (size_t)ip * 2097152 + 1572864;
    } else if (idx < 7680) {
        idx -= 6144;
        const int ip = idx / 512; idx %= 512; K = 512; N = 1024;
        src = wkvc + (size_t)ip * 524288; dst = W2t + (size_t)ip * 524288;
    } else {
        idx -= 7680;
        const int ip = idx / 1024; idx %= 1024; K = 1024; N = 1024;
        src = wo + (size_t)ip * 1048576;  dst = W3t + (size_t)ip * 1048576;
    }
    const int tiles_x = N >> 5;
    const int n0 = (idx % tiles_x) * 32, k0 = (idx / tiles_x) * 32;

    __shared__ float tile[32][33];
    const int tx = threadIdx.x & 31, ty = threadIdx.x >> 5; // 32 x 8
#pragma unroll
    for (int d = 0; d < 4; ++d)
        tile[ty + d * 8][tx] = src[(size_t)(k0 + ty + d * 8) * N + n0 + tx];
    __syncthreads();
#pragma unroll
    for (int d = 0; d < 4; ++d)
        dst[(size_t)(n0 + ty + d * 8) * K + k0 + tx] = __float2bfloat16(tile[tx][ty + d * 8]);
}

// ---------------------------------------------------------------------------
// Straight cast of w_out[0..1] to bf16 in ORIGINAL [m][d] orientation
// (B-operand of the weight-fold GEMMs). 2*1024*1024 elems, 4/thread.
// ---------------------------------------------------------------------------
__global__ __launch_bounds__(256)
void cast_w3o(const float* __restrict__ wo, __hip_bfloat16* __restrict__ W3o)
{
    const size_t i = ((size_t)blockIdx.x * 256 + threadIdx.x) * 4;
    const float4 v = *(const float4*)(wo + i);
    __hip_bfloat16 o[4] = { __float2bfloat16(v.x), __float2bfloat16(v.y),
                            __float2bfloat16(v.z), __float2bfloat16(v.w) };
    *(uint2*)(W3o + i) = *(const uint2*)o;
}

// ---------------------------------------------------------------------------
// Folded bias: bf[j][n] = sum_d b_out[j][d] * W1[j+1][d][n]  (j = 0,1)
// W1t[n][d] is contiguous in d. fp32 accum.
// ---------------------------------------------------------------------------
__global__ __launch_bounds__(256)
void bfold_kernel(const float* __restrict__ b_out,
                  const __hip_bfloat16* __restrict__ W1t,
                  float* __restrict__ bf)
{
    const int idx = blockIdx.x * 256 + threadIdx.x;   // [0, 4096)
    const int j = idx >> 11, n = idx & 2047;
    const float* b = b_out + j * 1024;
    const __hip_bfloat16* w = W1t + ((size_t)(j + 1) * 2048 + n) * 1024;
    float s = 0.f;
#pragma unroll 4
    for (int d = 0; d < 1024; ++d) s += b[d] * __bfloat162float(w[d]);
    bf[idx] = s;
}

// ---------------------------------------------------------------------------
// 256x256 8-phase bf16 MFMA GEMM: C[M,N] = A[M,K] @ Bt[N,K]^T
// 512 thr = 8 waves (2Mx4N), per-wave 128x64 out, BK=64, dbuf LDS 128 KiB.
// 4 phases/K-tile; FIFO prefetch A0,B0,A1,B1 one tile ahead; counted
// s_waitcnt vmcnt(4); explicit tail tile (waits 4 -> 2 -> 0).
// XOR swizzle on 16B col-groups, pre-swizzled global src (rule 21).
// EPI: 0 = bf16 ; 1 = bf16 + bias ; 2 = fp32 + bias + resid
// ---------------------------------------------------------------------------
template <int EPI>
__global__ __launch_bounds__(512)
void gemm8p(const __hip_bfloat16* __restrict__ A,
            const __hip_bfloat16* __restrict__ Bt,
            void* __restrict__ Cv,
            const float* __restrict__ bias,
            const float* __restrict__ resid,
            int M, int N, int K, int lda)
{
    __shared__ __align__(16) char lds[131072];

    // bijective XCD swizzle (all grids are multiples of 8 workgroups)
    const int gx  = gridDim.x;
    const int nwg = gx * gridDim.y;
    const int bid = blockIdx.y * gx + blockIdx.x;
    const int swz = (bid & 7) * (nwg >> 3) + (bid >> 3);
    const int m0 = (swz / gx) * 256;
    const int n0 = (swz % gx) * 256;

    const int t    = threadIdx.x;
    const int w    = t >> 6;
    const int lane = t & 63;
    const int wr   = w >> 2;     // 0..1  (M half)
    const int wc   = w & 3;      // 0..3  (N quarter)
    const int fr   = lane & 15;
    const int ksl  = lane >> 4;

    floatx4 acc[8][4] = {};

    // ---- staging source bases (pre-swizzled col: key = local row & 7)
    const int tr   = t >> 3;                      // 0..63
    const int scol = ((t & 7) ^ (tr & 7)) << 3;
    const __hip_bfloat16* aG = A  + (size_t)(m0 + tr) * lda + scol;
    const __hip_bfloat16* bG = Bt + (size_t)(n0 + ((tr >> 5) * 64) + (tr & 31)) * K + scol;
    const int ldst = t * 16;                      // linear LDS dest

    // ---- ds_read per-thread base offsets (kk=1 via ^64)
    const int cg0 = ksl ^ (fr & 7);
    const int aO0 = (wr * 64 + fr) * 128 + cg0 * 16;
    const int bO0 = (wc * 32 + fr) * 128 + cg0 * 16;

    // LDS map per buffer (64 KiB): A-h0 @0, A-h1 @16384, B-h0 @32768, B-h1 @49152
    auto stageA = [&](char* buf, int h, int ka) {
        gload16(aG + ka + (size_t)(h * 64)       * lda, buf + h * 16384 + ldst);
        gload16(aG + ka + (size_t)(h * 64 + 128) * lda, buf + h * 16384 + 8192 + ldst);
    };
    auto stageB = [&](char* buf, int h, int kb) {
        gload16(bG + kb + (size_t)(h * 32)       * K, buf + 32768 + h * 16384 + ldst);
        gload16(bG + kb + (size_t)(h * 32 + 128) * K, buf + 32768 + h * 16384 + 8192 + ldst);
    };

    const char* bufC = lds;
    auto ldA = [&](int h, bf16x8 (&a)[2][4]) {
#pragma unroll
        for (int mm = 0; mm < 4; ++mm) {
            a[0][mm] = *(const bf16x8*)(bufC + h * 16384 + mm * 2048 + aO0);
            a[1][mm] = *(const bf16x8*)(bufC + h * 16384 + mm * 2048 + (aO0 ^ 64));
        }
    };
    auto ldB = [&](int h, bf16x8 (&b)[2][2]) {
#pragma unroll
        for (int nn = 0; nn < 2; ++nn) {
            b[0][nn] = *(const bf16x8*)(bufC + 32768 + h * 16384 + nn * 2048 + bO0);
            b[1][nn] = *(const bf16x8*)(bufC + 32768 + h * 16384 + nn * 2048 + (bO0 ^ 64));
        }
    };
    auto quad = [&](bf16x8 (&a)[2][4], bf16x8 (&b)[2][2], int mlo, int nlo) {
        __builtin_amdgcn_s_setprio(1);
#pragma unroll
        for (int kk = 0; kk < 2; ++kk)
#pragma unroll
            for (int mm = 0; mm < 4; ++mm)
#pragma unroll
                for (int nn = 0; nn < 2; ++nn)
                    acc[mlo + mm][nlo + nn] = __builtin_amdgcn_mfma_f32_16x16x32_bf16(
                        a[kk][mm], b[kk][nn], acc[mlo + mm][nlo + nn], 0, 0, 0);
        __builtin_amdgcn_s_setprio(0);
    };

    const int NT = K >> 6;

    // prologue: tile 0 -> buf0, FIFO order A0,B0,A1,B1
    stageA(lds, 0, 0);
    stageB(lds, 0, 0);
    stageA(lds, 1, 0);
    stageB(lds, 1, 0);
    VMCNT(4);
    RAW_BARRIER();

    bf16x8 a0[2][4], a1[2][4], b0[2][2], b1[2][2];

    for (int tt = 0; tt < NT - 1; ++tt) {
        bufC = lds + ((tt & 1) << 16);
        char* bufN = lds + (((tt + 1) & 1) << 16);
        const int kc = (tt + 1) << 6;
        // P0: read A-h0,B-h0(tt); prefetch A-h0(tt+1); MFMA quad(m0-3, n0-1)
        ldA(0, a0); ldB(0, b0);
        stageA(bufN, 0, kc);
        RAW_BARRIER(); __builtin_amdgcn_sched_barrier(0);
        quad(a0, b0, 0, 0);
        VMCNT(4); RAW_BARRIER();
        // P1: read A-h1(tt); prefetch B-h0(tt+1); MFMA quad(m4-7, n0-1)
        ldA(1, a1);
        stageB(bufN, 0, kc);
        RAW_BARRIER(); __builtin_amdgcn_sched_barrier(0);
        quad(a1, b0, 4, 0);
        VMCNT(4); RAW_BARRIER();
        // P2: read B-h1(tt); prefetch A-h1(tt+1); MFMA quad(m0-3, n2-3)
        ldB(1, b1);
        stageA(bufN, 1, kc);
        RAW_BARRIER(); __builtin_amdgcn_sched_barrier(0);
        quad(a0, b1, 0, 2);
        RAW_BARRIER();
        // P3: prefetch B-h1(tt+1); MFMA quad(m4-7, n2-3)
        stageB(bufN, 1, kc);
        RAW_BARRIER(); __builtin_amdgcn_sched_barrier(0);
        quad(a1, b1, 4, 2);
        VMCNT(4); RAW_BARRIER();
    }

    // tail tile NT-1 (no prefetch): waits shrink 2 -> 0
    bufC = lds + (((NT - 1) & 1) << 16);
    ldA(0, a0); ldB(0, b0);
    RAW_BARRIER(); __builtin_amdgcn_sched_barrier(0);
    quad(a0, b0, 0, 0);
    VMCNT(2); RAW_BARRIER();
    ldA(1, a1);
    RAW_BARRIER(); __builtin_amdgcn_sched_barrier(0);
    quad(a1, b0, 4, 0);
    VMCNT(0); RAW_BARRIER();
    ldB(1, b1);
    RAW_BARRIER(); __builtin_amdgcn_sched_barrier(0);
    quad(a0, b1, 0, 2);
    quad(a1, b1, 4, 2);

    // ---- epilogue
#pragma unroll
    for (int m = 0; m < 8; ++m) {
#pragma unroll
        for (int n = 0; n < 4; ++n) {
            const int col = n0 + wc * 64 + n * 16 + fr;
#pragma unroll
            for (int r = 0; r < 4; ++r) {
                const int row = m0 + wr * 128 + m * 16 + ksl * 4 + r;
                const size_t idx = (size_t)row * N + col;
                const float v = acc[m][n][r];
                if (EPI == 0) {
                    ((__hip_bfloat16*)Cv)[idx] = __float2bfloat16(v);
                } else if (EPI == 1) {
                    ((__hip_bfloat16*)Cv)[idx] = __float2bfloat16(v + bias[col]);
                } else {
                    ((float*)Cv)[idx] = resid[idx] + v + bias[col];
                }
            }
        }
    }
}

// ---------------------------------------------------------------------------
// Axial attention. One block (256 thr) per (group, self/cross).
// qkv: [N0,2048] = [q_self | k_self | v_self | q_cross]
// kvc: [k_cross | v_cross] slice of kvc3, row stride ldkv
// Output: oc[token*ldo + (cross?cross_off:0) + c], c in [0,512)
// ---------------------------------------------------------------------------
__global__ __launch_bounds__(256)
void attn_kernel(const __hip_bfloat16* __restrict__ qkv,
                 const __hip_bfloat16* __restrict__ kvc, int ldkv,
                 __hip_bfloat16* __restrict__ oc, int ldo, int cross_off,
                 int ip)
{
    __shared__ __align__(16) __hip_bfloat16 Qs[12][520];
    __shared__ __align__(16) __hip_bfloat16 Ks[12][520];
    __shared__ __align__(16) __hip_bfloat16 Vs[12][520];
    __shared__ float P[8][12][12];

    const int g = blockIdx.x;
    const bool cross = blockIdx.y != 0;
    const int tid = threadIdx.x;

    const int b  = g / 144;
    const int r1 = (g % 144) / 12;
    const int r2 = g % 12;
    int n_base, qstride, kvb, kvstride, tk;
    if (ip == 0) {          // attend over T
        n_base = b * 1728 + r1 * 12 + r2; qstride = 144;
        kvb = b * 432 + (r1 >> 1) * 6 + (r2 >> 1); kvstride = 36; tk = 12;
    } else if (ip == 1) {   // attend over LA
        n_base = b * 1728 + r1 * 144 + r2; qstride = 12;
        kvb = b * 432 + r1 * 36 + (r2 >> 1); kvstride = 6; tk = 6;
    } else {                // attend over LO
        n_base = b * 1728 + r1 * 144 + r2 * 12; qstride = 1;
        kvb = b * 432 + r1 * 36 + (r2 >> 1) * 6; kvstride = 1; tk = 6;
    }
    if (!cross) tk = 12;

    // ---- stage Q (12 rows x 512 bf16 = 64 uint4 per row)
    const int qoff = cross ? 1536 : 0;
    for (int idx = tid; idx < 12 * 64; idx += 256) {
        const int i = idx >> 6, c = idx & 63;
        const uint4* src = (const uint4*)(qkv + (size_t)(n_base + i * qstride) * 2048 + qoff);
        *(uint4*)(&Qs[i][c * 8]) = src[c];
    }
    // ---- stage K/V
    if (!cross) {
        for (int idx = tid; idx < 12 * 64; idx += 256) {
            const int j = idx >> 6, c = idx & 63;
            const __hip_bfloat16* row = qkv + (size_t)(n_base + j * qstride) * 2048;
            *(uint4*)(&Ks[j][c * 8]) = ((const uint4*)(row + 512))[c];
            *(uint4*)(&Vs[j][c * 8]) = ((const uint4*)(row + 1024))[c];
        }
    } else {
        for (int idx = tid; idx < tk * 64; idx += 256) {
            const int j = idx >> 6, c = idx & 63;
            const __hip_bfloat16* row = kvc + (size_t)(kvb + j * kvstride) * ldkv;
            *(uint4*)(&Ks[j][c * 8]) = ((const uint4*)(row))[c];
            *(uint4*)(&Vs[j][c * 8]) = ((const uint4*)(row + 512))[c];
        }
    }
    __syncthreads();

    // ---- dots: P[h][i][j] = (q_i . k_j) * E^-0.5
    const int ndots = 8 * 12 * tk;
    for (int idx = tid; idx < ndots; idx += 256) {
        const int h = idx / (12 * tk);
        const int rem = idx % (12 * tk);
        const int i = rem / tk, j = rem % tk;
        const __hip_bfloat162* q2 = (const __hip_bfloat162*)(&Qs[i][h * 64]);
        const __hip_bfloat162* k2 = (const __hip_bfloat162*)(&Ks[j][h * 64]);
        float s = 0.f;
#pragma unroll
        for (int e = 0; e < 32; ++e) {
            const float2 qf = __bfloat1622float2(q2[e]);
            const float2 kf = __bfloat1622float2(k2[e]);
            s += qf.x * kf.x + qf.y * kf.y;
        }
        P[h][i][j] = s * 0.125f;
    }
    __syncthreads();

    // ---- softmax over j
    if (tid < 96) {
        const int h = tid / 12, i = tid % 12;
        float mx = -1e30f;
        for (int j = 0; j < tk; ++j) mx = fmaxf(mx, P[h][i][j]);
        float sum = 0.f;
        for (int j = 0; j < tk; ++j) { const float e = __expf(P[h][i][j] - mx); P[h][i][j] = e; sum += e; }
        const float inv = 1.f / sum;
        for (int j = 0; j < tk; ++j) P[h][i][j] *= inv;
    }
    __syncthreads();

    // ---- out: o[i][c] = sum_j P[h][i][j] * V[j][c]
    for (int idx = tid; idx < 12 * 512; idx += 256) {
        const int i = idx >> 9, c = idx & 511;
        const int h = c >> 6;
        float a = 0.f;
        for (int j = 0; j < tk; ++j)
            a += P[h][i][j] * __bfloat162float(Vs[j][c]);
        oc[(size_t)(n_base + i * qstride) * ldo + (cross ? cross_off : 0) + c] = __float2bfloat16(a);
    }
}

// ---------------------------------------------------------------------------
extern "C" void kernel_launch(void* const* d_in, const int* in_sizes, int n_in,
                              void* d_out, int out_size, void* d_ws, size_t ws_size,
                              hipStream_t stream)
{
    (void)in_sizes; (void)n_in; (void)out_size; (void)ws_size;
    const float* x0        = (const float*)d_in[0];
    const float* x1        = (const float*)d_in[1];
    const float* wq_self   = (const float*)d_in[2];
    const float* wkv_self  = (const float*)d_in[3];
    const float* wq_cross  = (const float*)d_in[4];
    const float* wkv_cross = (const float*)d_in[5];
    const float* w_out     = (const float*)d_in[6];
    const float* b_out     = (const float*)d_in[7];

    // d_out doubles as the qkv scratch: 55296*2048*2 B == out_size*4 B exactly
    __hip_bfloat16* qkv = (__hip_bfloat16*)d_out;

    char* ws = (char*)d_ws;
    size_t off = 0;
    auto alloc = [&](size_t bytes) {
        void* p = ws + off;
        off += (bytes + 255) & ~(size_t)255;
        return p;
    };
    __hip_bfloat16* f0   = (__hip_bfloat16*)alloc((size_t)N0 * 1024 * 2);
    __hip_bfloat16* f1   = (__hip_bfloat16*)alloc((size_t)N1 * 512 * 2);
    __hip_bfloat16* kvc3 = (__hip_bfloat16*)alloc((size_t)N1 * 3072 * 2);
    __hip_bfloat16* W1t  = (__hip_bfloat16*)alloc((size_t)3 * 2048 * 1024 * 2);
    __hip_bfloat16* W2t  = (__hip_bfloat16*)alloc((size_t)3 * 1024 * 512 * 2);
    __hip_bfloat16* W3t  = (__hip_bfloat16*)alloc((size_t)3 * 1024 * 1024 * 2);
    __hip_bfloat16* W3o  = (__hip_bfloat16*)alloc((size_t)2 * 1024 * 1024 * 2);
    __hip_bfloat16* Wf   = (__hip_bfloat16*)alloc((size_t)2 * 2048 * 1024 * 2);
    float*          bfo  = (float*)alloc((size_t)2 * 2048 * 4);

    // ---- setup: layernorms, weight transposes, fold precompute
    ln_all<<<N0 + N1, 256, 0, stream>>>(x0, x1, f0, f1);
    transpose_all<<<10752, 256, 0, stream>>>(wq_self, wkv_self, wq_cross,
                                             wkv_cross, w_out, W1t, W2t, W3t);
    cast_w3o<<<2048, 256, 0, stream>>>(w_out, W3o);
    bfold_kernel<<<16, 256, 0, stream>>>(b_out, W1t, bfo);
    // WfT[ip-1][n][m] = sum_d W1t[ip][n][d] * W3o[ip-1][m][d]  (2048x1024, K=1024)
    for (int j = 0; j < 2; ++j)
        gemm8p<0><<<dim3(4, 8), 512, 0, stream>>>(
            W1t + (size_t)(j + 1) * 2048 * 1024, W3o + (size_t)j * 1024 * 1024,
            Wf + (size_t)j * 2048 * 1024, nullptr, nullptr, 2048, 1024, 1024, 1024);
    // all 3 cross-kv projections in one GEMM: [N1,512] @ [512,3072] -> kvc3
    gemm8p<0><<<dim3(12, 54), 512, 0, stream>>>(
        f1, W2t, kvc3, nullptr, nullptr, N1, 3072, 512, 512);

    // ---- 3 axial layers (out-projections of layers 0,1 folded away)
    for (int ip = 0; ip < 3; ++ip) {
        if (ip == 0) {
            gemm8p<0><<<dim3(8, 216), 512, 0, stream>>>(
                f0, W1t, qkv, nullptr, nullptr, N0, 2048, 1024, 1024);
        } else {
            gemm8p<1><<<dim3(8, 216), 512, 0, stream>>>(
                f0, Wf + (size_t)(ip - 1) * 2048 * 1024, qkv,
                bfo + (ip - 1) * 2048, nullptr, N0, 2048, 1024, 1024);
        }
        // attention: reads qkv + kvc3 slice, writes concat [o_self|o_cross] -> f0
        attn_kernel<<<dim3(4608, 2), 256, 0, stream>>>(
            qkv, kvc3 + ip * 1024, 3072, f0, 1024, 512, ip);
    }
    // final out-proj: f0 @ W3t[2] + b[2] + x0 -> d_out (fp32)
    gemm8p<2><<<dim3(4, 216), 512, 0, stream>>>(
        f0, W3t + (size_t)2 * 1024 * 1024, d_out, b_out + 2 * 1024, x0,
        N0, 1024, 1024, 1024);
}

// Round 6
// 1597.376 us; speedup vs baseline: 1.5039x; 1.0890x over previous
//
#include <hip/hip_runtime.h>
#include <hip/hip_bf16.h>

// ---------------------------------------------------------------------------
// MultiFieldAxialAttention on MI355X (gfx950)
// B=32, T=12, LA=12, LO=12, D0=1024, D1=512, H=8+8, E=64
//
// Folds: qkv_{ip+1} = concat_ip @ (W3[ip]@W1[ip+1]) + b@W1[ip+1]; all 3
// cross-KV projections in one N=3072 GEMM.
//
// Layout pipeline: layer-ip qkv GEMM gathers A rows via digit-permutation
// sigma (per-lane global_load_lds source) and writes qkv with attention
// axis INNERMOST (L0: t, L1: la, L2 = natural). Attention then reads 12
// contiguous rows (48KB) and writes 24KB contiguous concat. Final GEMM is
// natural-order (resid x0 + fp32 out).
// ---------------------------------------------------------------------------

typedef __bf16 bf16x8 __attribute__((ext_vector_type(8)));
typedef float floatx4 __attribute__((ext_vector_type(4)));

#define N0 55296   // 32*12*12*12 tokens of field0
#define N1 13824   // 32*12*6*6 tokens of field1

#define RAW_BARRIER() asm volatile("s_barrier" ::: "memory")
#define VMCNT(n) asm volatile("s_waitcnt vmcnt(" #n ")" ::: "memory")

__device__ __forceinline__ void gload16(const void* g, void* l) {
    __builtin_amdgcn_global_load_lds(
        (const __attribute__((address_space(1))) unsigned int*)g,
        (__attribute__((address_space(3))) unsigned int*)l, 16, 0, 0);
}

// Row map: C physical row i -> A physical row.  Digits of i in its layout:
// SIG 1: C=L0 (la,lo,t)   -> A natural (t,la,lo)
// SIG 2: C=L1 (t,lo,la)   -> A L0 (la,lo,t)
// SIG 3: C=natural(t,la,lo)-> A L1 (t,lo,la)
template <int SIG>
__device__ __forceinline__ int mapRow(int i) {
    if (SIG == 0) return i;
    const int b = i / 1728, r = i % 1728;
    const int d1 = r / 144, r2 = r % 144, d2 = r2 / 12, d3 = r2 % 12;
    if (SIG == 1) return b * 1728 + d3 * 144 + d1 * 12 + d2;
    if (SIG == 2) return b * 1728 + d3 * 144 + d2 * 12 + d1;
    return b * 1728 + d1 * 144 + d3 * 12 + d2;
}

// ---------------------------------------------------------------------------
// LayerNorm: fp32 in -> bf16 out, 1 block per row; single launch for x0+x1
// ---------------------------------------------------------------------------
template <int D>
__device__ __forceinline__ void ln_body(const float* __restrict__ xr,
                                        __hip_bfloat16* __restrict__ yr)
{
    const int tid = threadIdx.x;
    float vals[D / 256];
    float s = 0.f, q = 0.f;
#pragma unroll
    for (int k = 0; k < D / 256; ++k) {
        float v = xr[tid + k * 256];
        vals[k] = v; s += v; q += v * v;
    }
#pragma unroll
    for (int off = 32; off > 0; off >>= 1) {
        s += __shfl_xor(s, off);
        q += __shfl_xor(q, off);
    }
    __shared__ float rs[4], rq[4];
    const int w = tid >> 6;
    if ((tid & 63) == 0) { rs[w] = s; rq[w] = q; }
    __syncthreads();
    s = rs[0] + rs[1] + rs[2] + rs[3];
    q = rq[0] + rq[1] + rq[2] + rq[3];
    const float mean = s * (1.f / D);
    const float var  = q * (1.f / D) - mean * mean;
    const float rstd = rsqrtf(var + 1e-5f);
#pragma unroll
    for (int k = 0; k < D / 256; ++k)
        yr[tid + k * 256] = __float2bfloat16((vals[k] - mean) * rstd);
}

__global__ __launch_bounds__(256)
void ln_all(const float* __restrict__ x0, const float* __restrict__ x1,
            __hip_bfloat16* __restrict__ f0, __hip_bfloat16* __restrict__ f1)
{
    const int row = blockIdx.x;
    if (row < N0) {
        ln_body<1024>(x0 + (size_t)row * 1024, f0 + (size_t)row * 1024);
    } else {
        const int r = row - N0;
        ln_body<512>(x1 + (size_t)r * 512, f1 + (size_t)r * 512);
    }
}

// ---------------------------------------------------------------------------
// All 15 weight transposes in ONE launch. in [K][N] fp32 -> out [N][K] bf16.
// ---------------------------------------------------------------------------
__global__ __launch_bounds__(256)
void transpose_all(const float* __restrict__ wqs, const float* __restrict__ wkvs,
                   const float* __restrict__ wqc, const float* __restrict__ wkvc,
                   const float* __restrict__ wo,
                   __hip_bfloat16* __restrict__ W1t,
                   __hip_bfloat16* __restrict__ W2t,
                   __hip_bfloat16* __restrict__ W3t)
{
    int idx = blockIdx.x;
    const float* src;
    __hip_bfloat16* dst;
    int K, N;
    if (idx < 1536) {
        const int ip = idx / 512; idx %= 512; K = 1024; N = 512;
        src = wqs + (size_t)ip * 524288;  dst = W1t + (size_t)ip * 2097152;
    } else if (idx < 4608) {
        idx -= 1536;
        const int ip = idx / 1024; idx %= 1024; K = 1024; N = 1024;
        src = wkvs + (size_t)ip * 1048576; dst = W1t + (size_t)ip * 2097152 + 524288;
    } else if (idx < 6144) {
        idx -= 4608;
        const int ip = idx / 512; idx %= 512; K = 1024; N = 512;
        src = wqc + (size_t)ip * 524288;  dst = W1t + (size_t)ip * 2097152 + 1572864;
    } else if (idx < 7680) {
        idx -= 6144;
        const int ip = idx / 512; idx %= 512; K = 512; N = 1024;
        src = wkvc + (size_t)ip * 524288; dst = W2t + (size_t)ip * 524288;
    } else {
        idx -= 7680;
        const int ip = idx / 1024; idx %= 1024; K = 1024; N = 1024;
        src = wo + (size_t)ip * 1048576;  dst = W3t + (size_t)ip * 1048576;
    }
    const int tiles_x = N >> 5;
    const int n0 = (idx % tiles_x) * 32, k0 = (idx / tiles_x) * 32;

    __shared__ float tile[32][33];
    const int tx = threadIdx.x & 31, ty = threadIdx.x >> 5; // 32 x 8
#pragma unroll
    for (int d = 0; d < 4; ++d)
        tile[ty + d * 8][tx] = src[(size_t)(k0 + ty + d * 8) * N + n0 + tx];
    __syncthreads();
#pragma unroll
    for (int d = 0; d < 4; ++d)
        dst[(size_t)(n0 + ty + d * 8) * K + k0 + tx] = __float2bfloat16(tile[tx][ty + d * 8]);
}

// ---------------------------------------------------------------------------
// Straight cast of w_out[0..1] to bf16 in ORIGINAL [m][d] orientation
// ---------------------------------------------------------------------------
__global__ __launch_bounds__(256)
void cast_w3o(const float* __restrict__ wo, __hip_bfloat16* __restrict__ W3o)
{
    const size_t i = ((size_t)blockIdx.x * 256 + threadIdx.x) * 4;
    const float4 v = *(const float4*)(wo + i);
    __hip_bfloat16 o[4] = { __float2bfloat16(v.x), __float2bfloat16(v.y),
                            __float2bfloat16(v.z), __float2bfloat16(v.w) };
    *(uint2*)(W3o + i) = *(const uint2*)o;
}

// ---------------------------------------------------------------------------
// Folded bias: bf[j][n] = sum_d b_out[j][d] * W1[j+1][d][n]  (j = 0,1)
// ---------------------------------------------------------------------------
__global__ __launch_bounds__(256)
void bfold_kernel(const float* __restrict__ b_out,
                  const __hip_bfloat16* __restrict__ W1t,
                  float* __restrict__ bf)
{
    const int idx = blockIdx.x * 256 + threadIdx.x;   // [0, 4096)
    const int j = idx >> 11, n = idx & 2047;
    const float* b = b_out + j * 1024;
    const __hip_bfloat16* w = W1t + ((size_t)(j + 1) * 2048 + n) * 1024;
    float s = 0.f;
#pragma unroll 4
    for (int d = 0; d < 1024; ++d) s += b[d] * __bfloat162float(w[d]);
    bf[idx] = s;
}

// ---------------------------------------------------------------------------
// 256x256 8-phase bf16 MFMA GEMM: C[M,N] = A[sigma(M),K] @ Bt[N,K]^T
// 512 thr = 8 waves (2Mx4N), BK=64, dbuf LDS 128 KiB, counted vmcnt(4),
// XOR-swizzled LDS via pre-swizzled per-lane global source (rule 21).
// SIG selects the A-row gather permutation (0 = identity).
// EPI: 0 = bf16 ; 1 = bf16 + bias ; 2 = fp32 + bias + resid
// ---------------------------------------------------------------------------
template <int EPI, int SIG>
__global__ __launch_bounds__(512)
void gemm8p(const __hip_bfloat16* __restrict__ A,
            const __hip_bfloat16* __restrict__ Bt,
            void* __restrict__ Cv,
            const float* __restrict__ bias,
            const float* __restrict__ resid,
            int M, int N, int K, int lda)
{
    __shared__ __align__(16) char lds[131072];

    // bijective XCD swizzle (all grids are multiples of 8 workgroups)
    const int gx  = gridDim.x;
    const int nwg = gx * gridDim.y;
    const int bid = blockIdx.y * gx + blockIdx.x;
    const int swz = (bid & 7) * (nwg >> 3) + (bid >> 3);
    const int m0 = (swz / gx) * 256;
    const int n0 = (swz % gx) * 256;

    const int t    = threadIdx.x;
    const int w    = t >> 6;
    const int lane = t & 63;
    const int wr   = w >> 2;     // 0..1  (M half)
    const int wc   = w & 3;      // 0..3  (N quarter)
    const int fr   = lane & 15;
    const int ksl  = lane >> 4;

    floatx4 acc[8][4] = {};

    // ---- staging source bases (pre-swizzled col: key = local row & 7)
    const int tr   = t >> 3;                      // 0..63
    const int scol = ((t & 7) ^ (tr & 7)) << 3;
    const __hip_bfloat16* aP[4];
#pragma unroll
    for (int r = 0; r < 4; ++r)
        aP[r] = A + (size_t)mapRow<SIG>(m0 + tr + r * 64) * lda + scol;
    const __hip_bfloat16* bG = Bt + (size_t)(n0 + ((tr >> 5) * 64) + (tr & 31)) * K + scol;
    const int ldst = t * 16;                      // linear LDS dest

    // ---- ds_read per-thread base offsets (kk=1 via ^64)
    const int cg0 = ksl ^ (fr & 7);
    const int aO0 = (wr * 64 + fr) * 128 + cg0 * 16;
    const int bO0 = (wc * 32 + fr) * 128 + cg0 * 16;

    // LDS map per buffer (64 KiB): A-h0 @0, A-h1 @16384, B-h0 @32768, B-h1 @49152
    auto stageA = [&](char* buf, int h, int ka) {
        gload16(aP[h]     + ka, buf + h * 16384 + ldst);
        gload16(aP[h + 2] + ka, buf + h * 16384 + 8192 + ldst);
    };
    auto stageB = [&](char* buf, int h, int kb) {
        gload16(bG + kb + (size_t)(h * 32)       * K, buf + 32768 + h * 16384 + ldst);
        gload16(bG + kb + (size_t)(h * 32 + 128) * K, buf + 32768 + h * 16384 + 8192 + ldst);
    };

    const char* bufC = lds;
    auto ldA = [&](int h, bf16x8 (&a)[2][4]) {
#pragma unroll
        for (int mm = 0; mm < 4; ++mm) {
            a[0][mm] = *(const bf16x8*)(bufC + h * 16384 + mm * 2048 + aO0);
            a[1][mm] = *(const bf16x8*)(bufC + h * 16384 + mm * 2048 + (aO0 ^ 64));
        }
    };
    auto ldB = [&](int h, bf16x8 (&b)[2][2]) {
#pragma unroll
        for (int nn = 0; nn < 2; ++nn) {
            b[0][nn] = *(const bf16x8*)(bufC + 32768 + h * 16384 + nn * 2048 + bO0);
            b[1][nn] = *(const bf16x8*)(bufC + 32768 + h * 16384 + nn * 2048 + (bO0 ^ 64));
        }
    };
    auto quad = [&](bf16x8 (&a)[2][4], bf16x8 (&b)[2][2], int mlo, int nlo) {
        __builtin_amdgcn_s_setprio(1);
#pragma unroll
        for (int kk = 0; kk < 2; ++kk)
#pragma unroll
            for (int mm = 0; mm < 4; ++mm)
#pragma unroll
                for (int nn = 0; nn < 2; ++nn)
                    acc[mlo + mm][nlo + nn] = __builtin_amdgcn_mfma_f32_16x16x32_bf16(
                        a[kk][mm], b[kk][nn], acc[mlo + mm][nlo + nn], 0, 0, 0);
        __builtin_amdgcn_s_setprio(0);
    };

    const int NT = K >> 6;

    // prologue: tile 0 -> buf0, FIFO order A0,B0,A1,B1
    stageA(lds, 0, 0);
    stageB(lds, 0, 0);
    stageA(lds, 1, 0);
    stageB(lds, 1, 0);
    VMCNT(4);
    RAW_BARRIER();

    bf16x8 a0[2][4], a1[2][4], b0[2][2], b1[2][2];

    for (int tt = 0; tt < NT - 1; ++tt) {
        bufC = lds + ((tt & 1) << 16);
        char* bufN = lds + (((tt + 1) & 1) << 16);
        const int kc = (tt + 1) << 6;
        // P0
        ldA(0, a0); ldB(0, b0);
        stageA(bufN, 0, kc);
        RAW_BARRIER(); __builtin_amdgcn_sched_barrier(0);
        quad(a0, b0, 0, 0);
        VMCNT(4); RAW_BARRIER();
        // P1
        ldA(1, a1);
        stageB(bufN, 0, kc);
        RAW_BARRIER(); __builtin_amdgcn_sched_barrier(0);
        quad(a1, b0, 4, 0);
        VMCNT(4); RAW_BARRIER();
        // P2
        ldB(1, b1);
        stageA(bufN, 1, kc);
        RAW_BARRIER(); __builtin_amdgcn_sched_barrier(0);
        quad(a0, b1, 0, 2);
        RAW_BARRIER();
        // P3
        stageB(bufN, 1, kc);
        RAW_BARRIER(); __builtin_amdgcn_sched_barrier(0);
        quad(a1, b1, 4, 2);
        VMCNT(4); RAW_BARRIER();
    }

    // tail tile NT-1 (no prefetch): waits shrink 2 -> 0
    bufC = lds + (((NT - 1) & 1) << 16);
    ldA(0, a0); ldB(0, b0);
    RAW_BARRIER(); __builtin_amdgcn_sched_barrier(0);
    quad(a0, b0, 0, 0);
    VMCNT(2); RAW_BARRIER();
    ldA(1, a1);
    RAW_BARRIER(); __builtin_amdgcn_sched_barrier(0);
    quad(a1, b0, 4, 0);
    VMCNT(0); RAW_BARRIER();
    ldB(1, b1);
    RAW_BARRIER(); __builtin_amdgcn_sched_barrier(0);
    quad(a0, b1, 0, 2);
    quad(a1, b1, 4, 2);

    // ---- epilogue (C rows are physically linear)
#pragma unroll
    for (int m = 0; m < 8; ++m) {
#pragma unroll
        for (int n = 0; n < 4; ++n) {
            const int col = n0 + wc * 64 + n * 16 + fr;
#pragma unroll
            for (int r = 0; r < 4; ++r) {
                const int row = m0 + wr * 128 + m * 16 + ksl * 4 + r;
                const size_t idx = (size_t)row * N + col;
                const float v = acc[m][n][r];
                if (EPI == 0) {
                    ((__hip_bfloat16*)Cv)[idx] = __float2bfloat16(v);
                } else if (EPI == 1) {
                    ((__hip_bfloat16*)Cv)[idx] = __float2bfloat16(v + bias[col]);
                } else {
                    ((float*)Cv)[idx] = resid[idx] + v + bias[col];
                }
            }
        }
    }
}

// ---------------------------------------------------------------------------
// Fused axial attention (self + cross in one block), layout-contiguous.
// qkv rows [g*12, g*12+12) in layer layout L(ip): [q_self|k_self|v_self|q_cross]
// kvc: layer slice of kvc3 (row stride 3072): [k_cross(512) | v_cross(512)]
// out: concat [o_self|o_cross] rows [g*12, g*12+12), ld 1024 (layout L(ip))
// ---------------------------------------------------------------------------
__global__ __launch_bounds__(512)
void attn_fused(const __hip_bfloat16* __restrict__ qkv,
                const __hip_bfloat16* __restrict__ kvc,
                __hip_bfloat16* __restrict__ out, int ip)
{
    __shared__ __align__(16) __hip_bfloat16 R[12][2052];   // full qkv rows
    __shared__ __align__(16) __hip_bfloat16 KV[12][1032];  // K [0:512], V [512:1024]
    __shared__ __hip_bfloat16 P[16][12][12];               // 8 self + 8 cross

    const int g   = blockIdx.x;           // 4608 fibers
    const int tid = threadIdx.x;

    // decode fiber -> cross-kv base (g digits are in layout L(ip) order)
    const int b  = g / 144;
    const int u1 = (g / 12) % 12;
    const int u2 = g % 12;
    int kvb, kvstride, tkc;
    if (ip == 0) {        // L0 fiber coords (la, lo); kv along t
        kvb = b * 432 + (u1 >> 1) * 6 + (u2 >> 1); kvstride = 36; tkc = 12;
    } else if (ip == 1) { // L1 fiber coords (t, lo); kv along la'
        kvb = b * 432 + u1 * 36 + (u2 >> 1); kvstride = 6; tkc = 6;
    } else {              // natural fiber coords (t, la); kv along lo'
        kvb = b * 432 + u1 * 36 + (u2 >> 1) * 6; kvstride = 1; tkc = 6;
    }

    // ---- stage 12 full rows (48KB contiguous)
    const uint4* src = (const uint4*)(qkv + (size_t)g * 12 * 2048);
    for (int idx = tid; idx < 12 * 256; idx += 512) {
        const int row = idx >> 8, cg = idx & 255;
        *(uint4*)(&R[row][cg * 8]) = src[row * 256 + cg];
    }
    // ---- stage cross K/V (2KB per kv row)
    for (int idx = tid; idx < tkc * 128; idx += 512) {
        const int row = idx >> 7, cg = idx & 127;
        const uint4* kvr = (const uint4*)(kvc + (size_t)(kvb + row * kvstride) * 3072);
        *(uint4*)(&KV[row][cg * 8]) = kvr[cg];
    }
    __syncthreads();

    // ---- dots (self: 1152, cross: 8*12*tkc)
    const int nd_self = 8 * 12 * 12;
    const int nd = nd_self + 8 * 12 * tkc;
    for (int idx = tid; idx < nd; idx += 512) {
        int h, i, j;
        const __hip_bfloat162 *q2, *k2;
        bool self = idx < nd_self;
        if (self) {
            h = idx / 144; const int rem = idx % 144; i = rem / 12; j = rem % 12;
            q2 = (const __hip_bfloat162*)(&R[i][h * 64]);
            k2 = (const __hip_bfloat162*)(&R[j][512 + h * 64]);
        } else {
            const int x = idx - nd_self;
            h = x / (12 * tkc); const int rem = x % (12 * tkc); i = rem / tkc; j = rem % tkc;
            q2 = (const __hip_bfloat162*)(&R[i][1536 + h * 64]);
            k2 = (const __hip_bfloat162*)(&KV[j][h * 64]);
        }
        float s = 0.f;
#pragma unroll
        for (int e = 0; e < 32; ++e) {
            const float2 qf = __bfloat1622float2(q2[e]);
            const float2 kf = __bfloat1622float2(k2[e]);
            s += qf.x * kf.x + qf.y * kf.y;
        }
        P[self ? h : 8 + h][i][j] = __float2bfloat16(s * 0.125f);
    }
    __syncthreads();

    // ---- softmax over j (96 self rows + 96 cross rows)
    if (tid < 192) {
        const int half = tid / 96, h = (tid % 96) / 12, i = tid % 12;
        const int tk = half ? tkc : 12;
        __hip_bfloat16* p = &P[half * 8 + h][i][0];
        float v[12];
        float mx = -1e30f;
        for (int j = 0; j < tk; ++j) { v[j] = __bfloat162float(p[j]); mx = fmaxf(mx, v[j]); }
        float sum = 0.f;
        for (int j = 0; j < tk; ++j) { v[j] = __expf(v[j] - mx); sum += v[j]; }
        const float inv = 1.f / sum;
        for (int j = 0; j < tk; ++j) p[j] = __float2bfloat16(v[j] * inv);
    }
    __syncthreads();

    // ---- AV: 12 rows x 512 col-pairs; write uint (2x bf16) coalesced
    for (int idx = tid; idx < 12 * 512; idx += 512) {
        const int i = idx >> 9, c2 = idx & 511;
        const int col = c2 * 2;
        float a0 = 0.f, a1 = 0.f;
        if (c2 < 256) {               // self: V = R[:,1024:1536]
            const int h = col >> 6;
            for (int j = 0; j < 12; ++j) {
                const float p = __bfloat162float(P[h][i][j]);
                a0 += p * __bfloat162float(R[j][1024 + col]);
                a1 += p * __bfloat162float(R[j][1024 + col + 1]);
            }
        } else {                      // cross: V = KV[:,512:1024]
            const int cc = col - 512;
            const int h = cc >> 6;
            for (int j = 0; j < tkc; ++j) {
                const float p = __bfloat162float(P[8 + h][i][j]);
                a0 += p * __bfloat162float(KV[j][512 + cc]);
                a1 += p * __bfloat162float(KV[j][512 + cc + 1]);
            }
        }
        __hip_bfloat16 o[2] = { __float2bfloat16(a0), __float2bfloat16(a1) };
        *(uint*)(out + (size_t)(g * 12 + i) * 1024 + col) = *(const uint*)o;
    }
}

// ---------------------------------------------------------------------------
extern "C" void kernel_launch(void* const* d_in, const int* in_sizes, int n_in,
                              void* d_out, int out_size, void* d_ws, size_t ws_size,
                              hipStream_t stream)
{
    (void)in_sizes; (void)n_in; (void)out_size; (void)ws_size;
    const float* x0        = (const float*)d_in[0];
    const float* x1        = (const float*)d_in[1];
    const float* wq_self   = (const float*)d_in[2];
    const float* wkv_self  = (const float*)d_in[3];
    const float* wq_cross  = (const float*)d_in[4];
    const float* wkv_cross = (const float*)d_in[5];
    const float* w_out     = (const float*)d_in[6];
    const float* b_out     = (const float*)d_in[7];

    // d_out doubles as the qkv scratch: 55296*2048*2 B == out_size*4 B exactly
    __hip_bfloat16* qkv = (__hip_bfloat16*)d_out;

    char* ws = (char*)d_ws;
    size_t off = 0;
    auto alloc = [&](size_t bytes) {
        void* p = ws + off;
        off += (bytes + 255) & ~(size_t)255;
        return p;
    };
    __hip_bfloat16* f0   = (__hip_bfloat16*)alloc((size_t)N0 * 1024 * 2);
    __hip_bfloat16* f1   = (__hip_bfloat16*)alloc((size_t)N1 * 512 * 2);
    __hip_bfloat16* kvc3 = (__hip_bfloat16*)alloc((size_t)N1 * 3072 * 2);
    __hip_bfloat16* W1t  = (__hip_bfloat16*)alloc((size_t)3 * 2048 * 1024 * 2);
    __hip_bfloat16* W2t  = (__hip_bfloat16*)alloc((size_t)3 * 1024 * 512 * 2);
    __hip_bfloat16* W3t  = (__hip_bfloat16*)alloc((size_t)3 * 1024 * 1024 * 2);
    __hip_bfloat16* W3o  = (__hip_bfloat16*)alloc((size_t)2 * 1024 * 1024 * 2);
    __hip_bfloat16* Wf   = (__hip_bfloat16*)alloc((size_t)2 * 2048 * 1024 * 2);
    float*          bfo  = (float*)alloc((size_t)2 * 2048 * 4);

    // ---- setup
    ln_all<<<N0 + N1, 256, 0, stream>>>(x0, x1, f0, f1);
    transpose_all<<<10752, 256, 0, stream>>>(wq_self, wkv_self, wq_cross,
                                             wkv_cross, w_out, W1t, W2t, W3t);
    cast_w3o<<<2048, 256, 0, stream>>>(w_out, W3o);
    bfold_kernel<<<16, 256, 0, stream>>>(b_out, W1t, bfo);
    for (int j = 0; j < 2; ++j)
        gemm8p<0, 0><<<dim3(4, 8), 512, 0, stream>>>(
            W1t + (size_t)(j + 1) * 2048 * 1024, W3o + (size_t)j * 1024 * 1024,
            Wf + (size_t)j * 2048 * 1024, nullptr, nullptr, 2048, 1024, 1024, 1024);
    gemm8p<0, 0><<<dim3(12, 54), 512, 0, stream>>>(
        f1, W2t, kvc3, nullptr, nullptr, N1, 3072, 512, 512);

    // ---- 3 axial layers; qkv GEMM gathers A and writes layer layout L(ip)
    // ip=0: A natural (LN), SIG=1 -> L0 ; ip=1: A L0, SIG=2 -> L1 ;
    // ip=2: A L1, SIG=3 -> natural
    gemm8p<0, 1><<<dim3(8, 216), 512, 0, stream>>>(
        f0, W1t, qkv, nullptr, nullptr, N0, 2048, 1024, 1024);
    attn_fused<<<4608, 512, 0, stream>>>(qkv, kvc3, f0, 0);

    gemm8p<1, 2><<<dim3(8, 216), 512, 0, stream>>>(
        f0, Wf, qkv, bfo, nullptr, N0, 2048, 1024, 1024);
    attn_fused<<<4608, 512, 0, stream>>>(qkv, kvc3 + 1024, f0, 1);

    gemm8p<1, 3><<<dim3(8, 216), 512, 0, stream>>>(
        f0, Wf + (size_t)2048 * 1024, qkv, bfo + 2048, nullptr, N0, 2048, 1024, 1024);
    attn_fused<<<4608, 512, 0, stream>>>(qkv, kvc3 + 2048, f0, 2);

    // ---- final out-proj: f0 (natural) @ W3t[2] + b[2] + x0 -> d_out (fp32)
    gemm8p<2, 0><<<dim3(4, 216), 512, 0, stream>>>(
        f0, W3t + (size_t)2 * 1024 * 1024, d_out, b_out + 2 * 1024, x0,
        N0, 1024, 1024, 1024);
}